// Round 1
// baseline (4055.660 us; speedup 1.0000x reference)
//
#include <hip/hip_runtime.h>
#include <stdint.h>
#include <stddef.h>

#define VOCAB 32000
#define HID   1024
#define NB    32
#define SLEN  64
#define TLEN  64
#define G3    3072

typedef float          f32x4  __attribute__((ext_vector_type(4)));
typedef __bf16         bf16x8 __attribute__((ext_vector_type(8)));
typedef unsigned short u16x8  __attribute__((ext_vector_type(8)));
typedef unsigned short u16x4  __attribute__((ext_vector_type(4)));
typedef unsigned int   u32x4  __attribute__((ext_vector_type(4)));

union BfPun { u16x8 u; bf16x8 b; };

__device__ __forceinline__ unsigned short f2bf(float f) {
  unsigned int u = __builtin_bit_cast(unsigned int, f);
  u += 0x7FFFu + ((u >> 16) & 1u);   // RNE round to bf16
  return (unsigned short)(u >> 16);
}

// ---------------- converts / gathers / init ----------------

__global__ __launch_bounds__(256) void cvt_bf16(const float* __restrict__ in,
                                                unsigned short* __restrict__ out) {
  size_t idx = ((size_t)blockIdx.x * 256 + threadIdx.x) * 4;
  f32x4 v = *(const f32x4*)(in + idx);
  u16x4 o;
  o[0] = f2bf(v[0]); o[1] = f2bf(v[1]); o[2] = f2bf(v[2]); o[3] = f2bf(v[3]);
  *(u16x4*)(out + idx) = o;
}

// W_ih_d [3072][2048] -> W1 (cols 0..1023), W2 (cols 1024..2047), both bf16 [3072][1024]
__global__ __launch_bounds__(256) void cvt_split_d(const float* __restrict__ Wd,
                                                   unsigned short* __restrict__ W1,
                                                   unsigned short* __restrict__ W2) {
  int r = blockIdx.x, q = threadIdx.x;
  const float* src = Wd + (size_t)r * 2048;
  f32x4 v1 = *(const f32x4*)(src + q * 4);
  f32x4 v2 = *(const f32x4*)(src + 1024 + q * 4);
  u16x4 o1, o2;
  o1[0]=f2bf(v1[0]); o1[1]=f2bf(v1[1]); o1[2]=f2bf(v1[2]); o1[3]=f2bf(v1[3]);
  o2[0]=f2bf(v2[0]); o2[1]=f2bf(v2[1]); o2[2]=f2bf(v2[2]); o2[3]=f2bf(v2[3]);
  *(u16x4*)(W1 + (size_t)r * 1024 + q * 4) = o1;
  *(u16x4*)(W2 + (size_t)r * 1024 + q * 4) = o2;
}

__global__ __launch_bounds__(256) void gather_embed(const int* __restrict__ seqs,
                                                    const float* __restrict__ emb,
                                                    unsigned short* __restrict__ Aout,
                                                    int relu) {
  int r = blockIdx.x, q = threadIdx.x;
  int tok = seqs[r];
  f32x4 v = *(const f32x4*)(emb + (size_t)tok * HID + q * 4);
  if (relu) {
    v[0]=fmaxf(v[0],0.f); v[1]=fmaxf(v[1],0.f); v[2]=fmaxf(v[2],0.f); v[3]=fmaxf(v[3],0.f);
  }
  u16x4 o; o[0]=f2bf(v[0]); o[1]=f2bf(v[1]); o[2]=f2bf(v[2]); o[3]=f2bf(v[3]);
  *(u16x4*)(Aout + (size_t)r * HID + q * 4) = o;
}

// relu(thought) -> bf16, rows 32..127 zero-padded (M must be 128 for the GEMM tile)
__global__ __launch_bounds__(256) void gather_thought(const float* __restrict__ hfin,
                                                      unsigned short* __restrict__ Aout) {
  int r = blockIdx.x, q = threadIdx.x;
  u16x4 o = {0, 0, 0, 0};
  if (r < NB) {
    f32x4 v = *(const f32x4*)(hfin + (size_t)r * HID + q * 4);
    o[0]=f2bf(fmaxf(v[0],0.f)); o[1]=f2bf(fmaxf(v[1],0.f));
    o[2]=f2bf(fmaxf(v[2],0.f)); o[3]=f2bf(fmaxf(v[3],0.f));
  }
  *(u16x4*)(Aout + (size_t)r * HID + q * 4) = o;
}

__global__ __launch_bounds__(256) void zero_f32(float* __restrict__ p) {
  p[blockIdx.x * 256 + threadIdx.x] = 0.f;
}

// ---------------- bf16 MFMA GEMM: C = A[M,1024] * B[N,1024]^T (+ epilogue) ----------------
// 128x128 tile, BK=32, 4 waves; frag layout per guide (m89/m97 verified):
//   A/B: lane l holds 8 contiguous K at row (l&15), k0=(l>>4)*8 ;  D: col=l&15, row=(l>>4)*4+e
// MODE 0: out[r*N+c]            = v + bias[c]                       (thought proj -> t2)
// MODE 1: xpT[t][g][b][ci]      = v + bias[c];  r=b*64+t, g=c>>10   (encoder xp)
// MODE 2: xpT[t][g][b][ci]      = v + add2[b*3072+c]                (decoder xp, t2 has bias)
// MODE 3: out[b][t][c]          = v + bias[c];  r=t*32+b            (logits -> d_out)
template<int MODE>
__global__ __launch_bounds__(256) void gemm_bf16(const unsigned short* __restrict__ A,
                                                 const unsigned short* __restrict__ Bw,
                                                 const float* __restrict__ bias,
                                                 const float* __restrict__ add2,
                                                 float* __restrict__ out, int N) {
  __shared__ unsigned short Abuf[128 * 32];
  __shared__ unsigned short Bbuf[128 * 32];
  const int K = HID;
  int tid = threadIdx.x, lane = tid & 63, wid = tid >> 6;
  int bn = blockIdx.x, bm = blockIdx.y;
  int wrow = wid >> 1, wcol = wid & 1;
  f32x4 zero4 = {0.f, 0.f, 0.f, 0.f};
  f32x4 acc[4][4];
#pragma unroll
  for (int i = 0; i < 4; ++i)
#pragma unroll
    for (int j = 0; j < 4; ++j) acc[i][j] = zero4;

  int srow = tid >> 2, spart = tid & 3;  // 64 rows x 4 x 16B chunks per half-tile
  const unsigned short* Ag = A + ((size_t)bm * 128 + srow) * K + spart * 8;
  const unsigned short* Bg = Bw + ((size_t)bn * 128 + srow) * K + spart * 8;
  unsigned short* As = Abuf + srow * 32 + spart * 8;
  unsigned short* Bs = Bbuf + srow * 32 + spart * 8;

  for (int ks = 0; ks < 32; ++ks) {
    int k0 = ks * 32;
    u32x4 a0 = *(const u32x4*)(Ag + k0);
    u32x4 a1 = *(const u32x4*)(Ag + (size_t)64 * K + k0);
    u32x4 b0 = *(const u32x4*)(Bg + k0);
    u32x4 b1 = *(const u32x4*)(Bg + (size_t)64 * K + k0);
    __syncthreads();
    *(u32x4*)As = a0;
    *(u32x4*)(As + 64 * 32) = a1;
    *(u32x4*)Bs = b0;
    *(u32x4*)(Bs + 64 * 32) = b1;
    __syncthreads();
    bf16x8 af[4], bfr[4];
#pragma unroll
    for (int mi = 0; mi < 4; ++mi) {
      BfPun tpun;
      tpun.u = *(const u16x8*)(Abuf + (wrow * 64 + mi * 16 + (lane & 15)) * 32 + (lane >> 4) * 8);
      af[mi] = tpun.b;
    }
#pragma unroll
    for (int ni = 0; ni < 4; ++ni) {
      BfPun tpun;
      tpun.u = *(const u16x8*)(Bbuf + (wcol * 64 + ni * 16 + (lane & 15)) * 32 + (lane >> 4) * 8);
      bfr[ni] = tpun.b;
    }
#pragma unroll
    for (int mi = 0; mi < 4; ++mi)
#pragma unroll
      for (int ni = 0; ni < 4; ++ni)
        acc[mi][ni] = __builtin_amdgcn_mfma_f32_16x16x32_bf16(af[mi], bfr[ni], acc[mi][ni], 0, 0, 0);
  }

#pragma unroll
  for (int mi = 0; mi < 4; ++mi) {
    int rb = bm * 128 + wrow * 64 + mi * 16 + ((lane >> 4) << 2);
#pragma unroll
    for (int ni = 0; ni < 4; ++ni) {
      int c = bn * 128 + wcol * 64 + ni * 16 + (lane & 15);
#pragma unroll
      for (int e = 0; e < 4; ++e) {
        int r = rb + e;
        float v = acc[mi][ni][e];
        if (MODE == 0) {
          out[(size_t)r * N + c] = v + bias[c];
        } else if (MODE == 1) {
          int t = r & 63, b = r >> 6;
          int g = c >> 10, ci = c & 1023;
          out[(((size_t)t * 3 + g) * NB + b) * HID + ci] = v + bias[c];
        } else if (MODE == 2) {
          int t = r & 63, b = r >> 6;
          int g = c >> 10, ci = c & 1023;
          out[(((size_t)t * 3 + g) * NB + b) * HID + ci] = v + add2[(size_t)b * G3 + c];
        } else {
          int b = r & 31, t = r >> 5;
          out[((size_t)b * TLEN + t) * VOCAB + c] = v + bias[c];
        }
      }
    }
  }
}

// ---------------- fused GRU step (fp32) ----------------
// grid 256 blocks x 512 thr; thread=(b, ii in 0..3, ks in 0..3); i = blk*4+ii
// gh[i_gate][b] partials over K/4, LDS-reduce, then gates + masked update.
__global__ __launch_bounds__(512) void gru_step(const float* __restrict__ W_hh,
                                                const float* __restrict__ b_hh,
                                                const float* __restrict__ xpT,   // [3][NB][HID] for this t
                                                const float* __restrict__ h_src, // [NB][HID]
                                                float* __restrict__ h_dst,
                                                const int* __restrict__ lens, int t,
                                                unsigned short* __restrict__ hs_out) {
  __shared__ float red0[512], red1[512], red2[512];
  int tid = threadIdx.x;
  int b = tid & 31;
  int ii = (tid >> 5) & 3;
  int ks = tid >> 7;
  int i = blockIdx.x * 4 + ii;
  const f32x4* hp = (const f32x4*)(h_src + (size_t)b * HID + ks * 256);
  const f32x4* wr = (const f32x4*)(W_hh + (size_t)i * HID + ks * 256);
  const f32x4* wz = (const f32x4*)(W_hh + (size_t)(HID + i) * HID + ks * 256);
  const f32x4* wn = (const f32x4*)(W_hh + (size_t)(2 * HID + i) * HID + ks * 256);
  float ar = 0.f, az = 0.f, an = 0.f;
#pragma unroll 8
  for (int j = 0; j < 64; ++j) {
    f32x4 h4 = hp[j];
    f32x4 w = wr[j];
    ar += w[0]*h4[0] + w[1]*h4[1] + w[2]*h4[2] + w[3]*h4[3];
    w = wz[j];
    az += w[0]*h4[0] + w[1]*h4[1] + w[2]*h4[2] + w[3]*h4[3];
    w = wn[j];
    an += w[0]*h4[0] + w[1]*h4[1] + w[2]*h4[2] + w[3]*h4[3];
  }
  red0[tid] = ar; red1[tid] = az; red2[tid] = an;
  __syncthreads();
  if (tid < 128) {
    float sr = red0[tid] + red0[tid+128] + red0[tid+256] + red0[tid+384];
    float sz = red1[tid] + red1[tid+128] + red1[tid+256] + red1[tid+384];
    float sn = red2[tid] + red2[tid+128] + red2[tid+256] + red2[tid+384];
    int b2 = tid & 31;
    int i2 = blockIdx.x * 4 + (tid >> 5);
    float xr = xpT[((size_t)0 * NB + b2) * HID + i2];
    float xz = xpT[((size_t)1 * NB + b2) * HID + i2];
    float xn = xpT[((size_t)2 * NB + b2) * HID + i2];
    float rg = 1.f / (1.f + __expf(-(xr + sr + b_hh[i2])));
    float zg = 1.f / (1.f + __expf(-(xz + sz + b_hh[HID + i2])));
    float ng = tanhf(xn + rg * (sn + b_hh[2 * HID + i2]));
    float hold = h_src[(size_t)b2 * HID + i2];
    float hnew = (1.f - zg) * ng + zg * hold;
    if (lens) hnew = (t < lens[b2]) ? hnew : hold;   // packed-seq freeze
    h_dst[(size_t)b2 * HID + i2] = hnew;
    if (hs_out) hs_out[((size_t)t * NB + b2) * HID + i2] = f2bf(hnew);
  }
}

// ---------------- in-place row log_softmax on d_out [2048 rows x 32000] ----------------
__global__ __launch_bounds__(256) void log_softmax_rows(float* __restrict__ out) {
  size_t row = blockIdx.x;
  float* p = out + row * VOCAB;
  f32x4* p4 = (f32x4*)p;
  int tid = threadIdx.x;
  float m = -3.0e38f, s = 0.f;
  for (int j = tid; j < VOCAB / 4; j += 256) {
    f32x4 v = p4[j];
#pragma unroll
    for (int e = 0; e < 4; ++e) {
      float x = v[e];
      float nm = fmaxf(m, x);
      s = s * __expf(m - nm) + __expf(x - nm);
      m = nm;
    }
  }
#pragma unroll
  for (int off = 1; off < 64; off <<= 1) {
    float m2 = __shfl_xor(m, off, 64);
    float s2 = __shfl_xor(s, off, 64);
    float nm = fmaxf(m, m2);
    s = s * __expf(m - nm) + s2 * __expf(m2 - nm);
    m = nm;
  }
  __shared__ float ms[4], ss[4];
  if ((tid & 63) == 0) { ms[tid >> 6] = m; ss[tid >> 6] = s; }
  __syncthreads();
  float M = fmaxf(fmaxf(ms[0], ms[1]), fmaxf(ms[2], ms[3]));
  float S = ss[0]*__expf(ms[0]-M) + ss[1]*__expf(ms[1]-M) +
            ss[2]*__expf(ms[2]-M) + ss[3]*__expf(ms[3]-M);
  float lse = M + __logf(S);
  for (int j = tid; j < VOCAB / 4; j += 256) {
    f32x4 v = p4[j];
    v[0] -= lse; v[1] -= lse; v[2] -= lse; v[3] -= lse;
    p4[j] = v;
  }
}

// ---------------- host ----------------

extern "C" void kernel_launch(void* const* d_in, const int* in_sizes, int n_in,
                              void* d_out, int out_size, void* d_ws, size_t ws_size,
                              hipStream_t stream) {
  (void)in_sizes; (void)n_in; (void)out_size; (void)ws_size;
  const int*   input_seqs  = (const int*)d_in[0];
  const int*   target_seqs = (const int*)d_in[1];
  const int*   input_lens  = (const int*)d_in[2];
  const float* emb_enc = (const float*)d_in[3];
  const float* W_ih_e  = (const float*)d_in[4];
  const float* W_hh_e  = (const float*)d_in[5];
  const float* b_ih_e  = (const float*)d_in[6];
  const float* b_hh_e  = (const float*)d_in[7];
  const float* emb_dec = (const float*)d_in[8];
  const float* W_ih_d  = (const float*)d_in[9];
  const float* W_hh_d  = (const float*)d_in[10];
  const float* b_ih_d  = (const float*)d_in[11];
  const float* b_hh_d  = (const float*)d_in[12];
  const float* W_out   = (const float*)d_in[13];
  const float* b_out   = (const float*)d_in[14];
  float* out = (float*)d_out;

  char* p = (char*)d_ws;
  auto take = [&](size_t n) { char* q = p; p += (n + 255) & ~(size_t)255; return q; };
  unsigned short* Wbf_e  = (unsigned short*)take((size_t)G3 * HID * 2);
  unsigned short* Wbf_1d = (unsigned short*)take((size_t)G3 * HID * 2);
  unsigned short* Wbf_2d = (unsigned short*)take((size_t)G3 * HID * 2);
  unsigned short* Wbf_o  = (unsigned short*)take((size_t)VOCAB * HID * 2);
  unsigned short* A_ed   = (unsigned short*)take((size_t)2048 * HID * 2);  // shared enc/dec A
  unsigned short* A_th   = (unsigned short*)take((size_t)128 * HID * 2);
  unsigned short* A_hs   = (unsigned short*)take((size_t)2048 * HID * 2);
  float* xpT = (float*)take((size_t)64 * 3 * NB * HID * 4);                // shared enc/dec xp
  float* t2  = (float*)take((size_t)128 * G3 * 4);
  float* h0  = (float*)take((size_t)NB * HID * 4);
  float* h1  = (float*)take((size_t)NB * HID * 4);

  // weight converts (fp32 -> bf16)
  cvt_bf16<<<dim3((G3 * HID) / 1024), 256, 0, stream>>>(W_ih_e, Wbf_e);
  cvt_split_d<<<dim3(G3), 256, 0, stream>>>(W_ih_d, Wbf_1d, Wbf_2d);
  cvt_bf16<<<dim3((VOCAB * HID) / 1024), 256, 0, stream>>>(W_out, Wbf_o);

  // ---- encoder ----
  gather_embed<<<dim3(NB * SLEN), 256, 0, stream>>>(input_seqs, emb_enc, A_ed, 0);
  gemm_bf16<1><<<dim3(G3 / 128, 2048 / 128), 256, 0, stream>>>(A_ed, Wbf_e, b_ih_e, nullptr, xpT, G3);
  zero_f32<<<dim3(128), 256, 0, stream>>>(h0);
  for (int t = 0; t < SLEN; ++t) {
    const float* hs = (t & 1) ? h1 : h0;
    float* hd = (t & 1) ? h0 : h1;
    gru_step<<<dim3(256), 512, 0, stream>>>(W_hh_e, b_hh_e, xpT + (size_t)t * 3 * NB * HID,
                                            hs, hd, input_lens, t, nullptr);
  }
  // final encoder hidden ("thought") now in h0

  // ---- decoder pre ----
  gather_thought<<<dim3(128), 256, 0, stream>>>(h0, A_th);
  gemm_bf16<0><<<dim3(G3 / 128, 1), 256, 0, stream>>>(A_th, Wbf_2d, b_ih_d, nullptr, t2, G3);
  gather_embed<<<dim3(NB * TLEN), 256, 0, stream>>>(target_seqs, emb_dec, A_ed, 1);
  gemm_bf16<2><<<dim3(G3 / 128, 2048 / 128), 256, 0, stream>>>(A_ed, Wbf_1d, nullptr, t2, xpT, G3);

  // ---- decoder scan ----
  zero_f32<<<dim3(128), 256, 0, stream>>>(h0);
  for (int t = 0; t < TLEN; ++t) {
    const float* hs = (t & 1) ? h1 : h0;
    float* hd = (t & 1) ? h0 : h1;
    gru_step<<<dim3(256), 512, 0, stream>>>(W_hh_d, b_hh_d, xpT + (size_t)t * 3 * NB * HID,
                                            hs, hd, nullptr, t, A_hs);
  }

  // ---- logits (direct to d_out) + in-place log_softmax ----
  gemm_bf16<3><<<dim3(VOCAB / 128, 2048 / 128), 256, 0, stream>>>(A_hs, Wbf_o, b_out, nullptr, out, VOCAB);
  log_softmax_rows<<<dim3(NB * TLEN), 256, 0, stream>>>(out);
}

// Round 2
// 3035.805 us; speedup vs baseline: 1.3359x; 1.3359x over previous
//
#include <hip/hip_runtime.h>
#include <stdint.h>
#include <stddef.h>

#define VOCAB 32000
#define HID   1024
#define NB    32
#define SLEN  64
#define TLEN  64
#define G3    3072

typedef float          f32x4  __attribute__((ext_vector_type(4)));
typedef __bf16         bf16x8 __attribute__((ext_vector_type(8)));
typedef unsigned short u16x8  __attribute__((ext_vector_type(8)));
typedef unsigned short u16x4  __attribute__((ext_vector_type(4)));
typedef unsigned int   u32x4  __attribute__((ext_vector_type(4)));

union BfPun { u16x8 u; bf16x8 b; };

__device__ __forceinline__ unsigned short f2bf(float f) {
  unsigned int u = __builtin_bit_cast(unsigned int, f);
  u += 0x7FFFu + ((u >> 16) & 1u);   // RNE round to bf16
  return (unsigned short)(u >> 16);
}

// ---------------- converts / gathers / init ----------------

__global__ __launch_bounds__(256) void cvt_bf16(const float* __restrict__ in,
                                                unsigned short* __restrict__ out) {
  size_t idx = ((size_t)blockIdx.x * 256 + threadIdx.x) * 4;
  f32x4 v = *(const f32x4*)(in + idx);
  u16x4 o;
  o[0] = f2bf(v[0]); o[1] = f2bf(v[1]); o[2] = f2bf(v[2]); o[3] = f2bf(v[3]);
  *(u16x4*)(out + idx) = o;
}

// W_ih_d [3072][2048] -> W1 (cols 0..1023), W2 (cols 1024..2047), both bf16 [3072][1024]
__global__ __launch_bounds__(256) void cvt_split_d(const float* __restrict__ Wd,
                                                   unsigned short* __restrict__ W1,
                                                   unsigned short* __restrict__ W2) {
  int r = blockIdx.x, q = threadIdx.x;
  const float* src = Wd + (size_t)r * 2048;
  f32x4 v1 = *(const f32x4*)(src + q * 4);
  f32x4 v2 = *(const f32x4*)(src + 1024 + q * 4);
  u16x4 o1, o2;
  o1[0]=f2bf(v1[0]); o1[1]=f2bf(v1[1]); o1[2]=f2bf(v1[2]); o1[3]=f2bf(v1[3]);
  o2[0]=f2bf(v2[0]); o2[1]=f2bf(v2[1]); o2[2]=f2bf(v2[2]); o2[3]=f2bf(v2[3]);
  *(u16x4*)(W1 + (size_t)r * 1024 + q * 4) = o1;
  *(u16x4*)(W2 + (size_t)r * 1024 + q * 4) = o2;
}

// W_hh [3H][H] fp32 -> per-scan-block reordered bf16: Wv[blk][g*16+il][k],
// blk = i>>4, il = i&15  (block owns 16 i's x 3 gates = 48 rows)
__global__ __launch_bounds__(256) void cvt_whh(const float* __restrict__ W,
                                               unsigned short* __restrict__ Wv) {
  int r = blockIdx.x;              // 0..3071 original row
  int g = r >> 10, i = r & 1023;
  int blk = i >> 4, il = i & 15;
  size_t dst = ((size_t)blk * 48 + g * 16 + il) * HID;
  int q = threadIdx.x;
  f32x4 v = *(const f32x4*)(W + (size_t)r * HID + q * 4);
  u16x4 o;
  o[0]=f2bf(v[0]); o[1]=f2bf(v[1]); o[2]=f2bf(v[2]); o[3]=f2bf(v[3]);
  *(u16x4*)(Wv + dst + q * 4) = o;
}

__global__ __launch_bounds__(256) void gather_embed(const int* __restrict__ seqs,
                                                    const float* __restrict__ emb,
                                                    unsigned short* __restrict__ Aout,
                                                    int relu) {
  int r = blockIdx.x, q = threadIdx.x;
  int tok = seqs[r];
  f32x4 v = *(const f32x4*)(emb + (size_t)tok * HID + q * 4);
  if (relu) {
    v[0]=fmaxf(v[0],0.f); v[1]=fmaxf(v[1],0.f); v[2]=fmaxf(v[2],0.f); v[3]=fmaxf(v[3],0.f);
  }
  u16x4 o; o[0]=f2bf(v[0]); o[1]=f2bf(v[1]); o[2]=f2bf(v[2]); o[3]=f2bf(v[3]);
  *(u16x4*)(Aout + (size_t)r * HID + q * 4) = o;
}

// relu(thought) -> bf16, rows 32..127 zero-padded
__global__ __launch_bounds__(256) void gather_thought(const float* __restrict__ hfin,
                                                      unsigned short* __restrict__ Aout) {
  int r = blockIdx.x, q = threadIdx.x;
  u16x4 o = {0, 0, 0, 0};
  if (r < NB) {
    f32x4 v = *(const f32x4*)(hfin + (size_t)r * HID + q * 4);
    o[0]=f2bf(fmaxf(v[0],0.f)); o[1]=f2bf(fmaxf(v[1],0.f));
    o[2]=f2bf(fmaxf(v[2],0.f)); o[3]=f2bf(fmaxf(v[3],0.f));
  }
  *(u16x4*)(Aout + (size_t)r * HID + q * 4) = o;
}

__global__ __launch_bounds__(256) void zero_f32(float* __restrict__ p) {
  p[blockIdx.x * 256 + threadIdx.x] = 0.f;
}

// ---------------- bf16 MFMA GEMM: C = A[M,1024] * B[N,1024]^T (+ epilogue) ----------------
// 1-D grid; XCD-chunked swizzle + (MT x 4) supertile: bm fast inside 4-wide column groups.
// MODE 0: out[r*N+c]       = v + bias[c]
// MODE 1: xpT[t][g][b][ci] = v + bias[c];  r=b*64+t
// MODE 2: xpT[t][g][b][ci] = v + add2[b*3072+c]
// MODE 3: out[b][t][c]     = v + bias[c];  r=t*32+b   (logits -> d_out)
template<int MODE, int MT>
__global__ __launch_bounds__(256) void gemm_bf16(const unsigned short* __restrict__ A,
                                                 const unsigned short* __restrict__ Bw,
                                                 const float* __restrict__ bias,
                                                 const float* __restrict__ add2,
                                                 float* __restrict__ out, int N) {
  __shared__ unsigned short Abuf[128 * 32];
  __shared__ unsigned short Bbuf[128 * 32];
  const int K = HID;
  int tid = threadIdx.x, lane = tid & 63, wid = tid >> 6;
  // swizzle: XCD-contiguous chunks, then bm-fast supertiles of 4 columns
  int nwg = gridDim.x;
  int u = (blockIdx.x & 7) * (nwg >> 3) + (blockIdx.x >> 3);
  int g = u / (MT * 4);
  int r_ = u - g * (MT * 4);
  int bm = r_ % MT;
  int bn = g * 4 + r_ / MT;
  int wrow = wid >> 1, wcol = wid & 1;
  f32x4 zero4 = {0.f, 0.f, 0.f, 0.f};
  f32x4 acc[4][4];
#pragma unroll
  for (int i = 0; i < 4; ++i)
#pragma unroll
    for (int j = 0; j < 4; ++j) acc[i][j] = zero4;

  int srow = tid >> 2, spart = tid & 3;
  const unsigned short* Ag = A + ((size_t)bm * 128 + srow) * K + spart * 8;
  const unsigned short* Bg = Bw + ((size_t)bn * 128 + srow) * K + spart * 8;
  unsigned short* As = Abuf + srow * 32 + spart * 8;
  unsigned short* Bs = Bbuf + srow * 32 + spart * 8;

  for (int ks = 0; ks < 32; ++ks) {
    int k0 = ks * 32;
    u32x4 a0 = *(const u32x4*)(Ag + k0);
    u32x4 a1 = *(const u32x4*)(Ag + (size_t)64 * K + k0);
    u32x4 b0 = *(const u32x4*)(Bg + k0);
    u32x4 b1 = *(const u32x4*)(Bg + (size_t)64 * K + k0);
    __syncthreads();
    *(u32x4*)As = a0;
    *(u32x4*)(As + 64 * 32) = a1;
    *(u32x4*)Bs = b0;
    *(u32x4*)(Bs + 64 * 32) = b1;
    __syncthreads();
    bf16x8 af[4], bfr[4];
#pragma unroll
    for (int mi = 0; mi < 4; ++mi) {
      BfPun tpun;
      tpun.u = *(const u16x8*)(Abuf + (wrow * 64 + mi * 16 + (lane & 15)) * 32 + (lane >> 4) * 8);
      af[mi] = tpun.b;
    }
#pragma unroll
    for (int ni = 0; ni < 4; ++ni) {
      BfPun tpun;
      tpun.u = *(const u16x8*)(Bbuf + (wcol * 64 + ni * 16 + (lane & 15)) * 32 + (lane >> 4) * 8);
      bfr[ni] = tpun.b;
    }
#pragma unroll
    for (int mi = 0; mi < 4; ++mi)
#pragma unroll
      for (int ni = 0; ni < 4; ++ni)
        acc[mi][ni] = __builtin_amdgcn_mfma_f32_16x16x32_bf16(af[mi], bfr[ni], acc[mi][ni], 0, 0, 0);
  }

#pragma unroll
  for (int mi = 0; mi < 4; ++mi) {
    int rb = bm * 128 + wrow * 64 + mi * 16 + ((lane >> 4) << 2);
#pragma unroll
    for (int ni = 0; ni < 4; ++ni) {
      int c = bn * 128 + wcol * 64 + ni * 16 + (lane & 15);
#pragma unroll
      for (int e = 0; e < 4; ++e) {
        int r = rb + e;
        float v = acc[mi][ni][e];
        if (MODE == 0) {
          out[(size_t)r * N + c] = v + bias[c];
        } else if (MODE == 1) {
          int t = r & 63, b = r >> 6;
          int gg = c >> 10, ci = c & 1023;
          out[(((size_t)t * 3 + gg) * NB + b) * HID + ci] = v + bias[c];
        } else if (MODE == 2) {
          int t = r & 63, b = r >> 6;
          int gg = c >> 10, ci = c & 1023;
          out[(((size_t)t * 3 + gg) * NB + b) * HID + ci] = v + add2[(size_t)b * G3 + c];
        } else {
          int b = r & 31, t = r >> 5;
          out[((size_t)b * TLEN + t) * VOCAB + c] = v + bias[c];
        }
      }
    }
  }
}

// ---------------- persistent GRU scan (MFMA, W_hh in registers) ----------------
// 64 blocks x 192 threads (3 waves). Block owns i-range [blk*16, blk*16+16),
// 48 W rows (3 gates x 16 i) = 3 M-tiles, wave w holds M-tile w in VGPRs.
// Per step: gh = W_hh_blk @ h^T via MFMA -> LDS -> gate epilogue -> write h slice
// (bf16 exchange buffer, double-buffered) -> software grid barrier.

__device__ __forceinline__ void grid_bar(int* bar, int nblk) {
  __syncthreads();
  if (threadIdx.x == 0) {
    __threadfence();   // release: h slice writes visible device-wide
    int g = __hip_atomic_load(&bar[1], __ATOMIC_RELAXED, __HIP_MEMORY_SCOPE_AGENT);
    int a = __hip_atomic_fetch_add(&bar[0], 1, __ATOMIC_ACQ_REL, __HIP_MEMORY_SCOPE_AGENT);
    if (a == nblk - 1) {
      __hip_atomic_store(&bar[0], 0, __ATOMIC_RELAXED, __HIP_MEMORY_SCOPE_AGENT);
      __hip_atomic_fetch_add(&bar[1], 1, __ATOMIC_RELEASE, __HIP_MEMORY_SCOPE_AGENT);
    } else {
      while (__hip_atomic_load(&bar[1], __ATOMIC_RELAXED, __HIP_MEMORY_SCOPE_AGENT) == g)
        __builtin_amdgcn_s_sleep(2);
    }
    __threadfence();   // acquire: invalidate stale L1/L2 before reading h
  }
  __syncthreads();
}

__global__ __launch_bounds__(192, 1) void gru_scan(
    const unsigned short* __restrict__ Wv,   // [64][48][1024] bf16
    const float* __restrict__ b_hh,
    const float* __restrict__ xpT,           // [T][3][NB][HID]
    unsigned short* __restrict__ hbf,        // [2][NB][HID] bf16, zeroed
    const int* __restrict__ lens,            // null => no freeze (decoder)
    unsigned short* __restrict__ hs_out,     // null for encoder; [T*NB][HID] bf16
    float* __restrict__ hfin,                // final h fp32 (encoder) or null
    int* __restrict__ bar, int nsteps) {
  __shared__ float gh[48][33];
  __shared__ float h32[32][16];
  __shared__ float bhh_s[48];
  __shared__ int   lens_s[32];
  int tid = threadIdx.x, lane = tid & 63, w = tid >> 6;
  int blk = blockIdx.x, i0 = blk * 16;

  if (tid < 32) lens_s[tid] = lens ? lens[tid] : 0x7fffffff;
  if (tid >= 64 && tid < 112) {
    int q = tid - 64;
    bhh_s[q] = b_hh[(size_t)(q >> 4) * HID + i0 + (q & 15)];
  }
  for (int x = tid; x < 512; x += 192) h32[x >> 4][x & 15] = 0.f;

  // hold this block's W_hh slice as A-fragments in registers (32 k-steps x 4 VGPR)
  const unsigned short* Wb = Wv + ((size_t)blk * 48 + w * 16 + (lane & 15)) * HID + (lane >> 4) * 8;
  bf16x8 af[32];
#pragma unroll
  for (int ks = 0; ks < 32; ++ks) { BfPun t_; t_.u = *(const u16x8*)(Wb + ks * 32); af[ks] = t_.b; }
  __syncthreads();

  for (int t = 0; t < nsteps; ++t) {
    const unsigned short* hb = hbf + ((t & 1) ? (size_t)NB * HID : 0);
    unsigned short*       hn = hbf + ((t & 1) ? 0 : (size_t)NB * HID);
    const unsigned short* hp = hb + (size_t)(lane & 15) * HID + (lane >> 4) * 8;
    f32x4 acc0 = {0.f, 0.f, 0.f, 0.f}, acc1 = {0.f, 0.f, 0.f, 0.f};
#pragma unroll
    for (int ks = 0; ks < 32; ++ks) {
      BfPun b0, b1;
      b0.u = *(const u16x8*)(hp + ks * 32);
      b1.u = *(const u16x8*)(hp + (size_t)16 * HID + ks * 32);
      acc0 = __builtin_amdgcn_mfma_f32_16x16x32_bf16(af[ks], b0.b, acc0, 0, 0, 0);
      acc1 = __builtin_amdgcn_mfma_f32_16x16x32_bf16(af[ks], b1.b, acc1, 0, 0, 0);
    }
    // D frag: row(vr within tile) = (lane>>4)*4+e, col(b) = lane&15
    int vr0 = w * 16 + (lane >> 4) * 4, cb = lane & 15;
#pragma unroll
    for (int e = 0; e < 4; ++e) {
      gh[vr0 + e][cb]      = acc0[e];
      gh[vr0 + e][16 + cb] = acc1[e];
    }
    __syncthreads();

    const float* xp_t = xpT + (size_t)t * 3 * NB * HID;
    for (int idx = tid; idx < 512; idx += 192) {
      int il = idx & 15, b = idx >> 4;
      float xr = xp_t[((size_t)0 * NB + b) * HID + i0 + il];
      float xz = xp_t[((size_t)1 * NB + b) * HID + i0 + il];
      float xn = xp_t[((size_t)2 * NB + b) * HID + i0 + il];
      float sr = gh[il][b], sz = gh[16 + il][b], sn = gh[32 + il][b];
      float rg = 1.f / (1.f + __expf(-(xr + sr + bhh_s[il])));
      float zg = 1.f / (1.f + __expf(-(xz + sz + bhh_s[16 + il])));
      float ng = tanhf(xn + rg * (sn + bhh_s[32 + il]));
      float hold = h32[b][il];
      float hnew = (1.f - zg) * ng + zg * hold;
      if (t >= lens_s[b]) hnew = hold;            // packed-seq freeze
      h32[b][il] = hnew;
      hn[(size_t)b * HID + i0 + il] = f2bf(hnew);
      if (hs_out) hs_out[((size_t)t * NB + b) * HID + i0 + il] = f2bf(hnew);
    }
    grid_bar(bar, gridDim.x);
  }

  if (hfin) {
    for (int idx = tid; idx < 512; idx += 192) {
      int il = idx & 15, b = idx >> 4;
      hfin[(size_t)b * HID + i0 + il] = h32[b][il];
    }
  }
}

// ---------------- in-place row log_softmax on d_out [2048 rows x 32000] ----------------
__global__ __launch_bounds__(256) void log_softmax_rows(float* __restrict__ out) {
  size_t row = blockIdx.x;
  float* p = out + row * VOCAB;
  f32x4* p4 = (f32x4*)p;
  int tid = threadIdx.x;
  float m = -3.0e38f, s = 0.f;
  for (int j = tid; j < VOCAB / 4; j += 256) {
    f32x4 v = p4[j];
#pragma unroll
    for (int e = 0; e < 4; ++e) {
      float x = v[e];
      float nm = fmaxf(m, x);
      s = s * __expf(m - nm) + __expf(x - nm);
      m = nm;
    }
  }
#pragma unroll
  for (int off = 1; off < 64; off <<= 1) {
    float m2 = __shfl_xor(m, off, 64);
    float s2 = __shfl_xor(s, off, 64);
    float nm = fmaxf(m, m2);
    s = s * __expf(m - nm) + s2 * __expf(m2 - nm);
    m = nm;
  }
  __shared__ float ms[4], ss[4];
  if ((tid & 63) == 0) { ms[tid >> 6] = m; ss[tid >> 6] = s; }
  __syncthreads();
  float M = fmaxf(fmaxf(ms[0], ms[1]), fmaxf(ms[2], ms[3]));
  float S = ss[0]*__expf(ms[0]-M) + ss[1]*__expf(ms[1]-M) +
            ss[2]*__expf(ms[2]-M) + ss[3]*__expf(ms[3]-M);
  float lse = M + __logf(S);
  for (int j = tid; j < VOCAB / 4; j += 256) {
    f32x4 v = p4[j];
    v[0] -= lse; v[1] -= lse; v[2] -= lse; v[3] -= lse;
    p4[j] = v;
  }
}

// ---------------- host ----------------

extern "C" void kernel_launch(void* const* d_in, const int* in_sizes, int n_in,
                              void* d_out, int out_size, void* d_ws, size_t ws_size,
                              hipStream_t stream) {
  (void)in_sizes; (void)n_in; (void)out_size; (void)ws_size;
  const int*   input_seqs  = (const int*)d_in[0];
  const int*   target_seqs = (const int*)d_in[1];
  const int*   input_lens  = (const int*)d_in[2];
  const float* emb_enc = (const float*)d_in[3];
  const float* W_ih_e  = (const float*)d_in[4];
  const float* W_hh_e  = (const float*)d_in[5];
  const float* b_ih_e  = (const float*)d_in[6];
  const float* b_hh_e  = (const float*)d_in[7];
  const float* emb_dec = (const float*)d_in[8];
  const float* W_ih_d  = (const float*)d_in[9];
  const float* W_hh_d  = (const float*)d_in[10];
  const float* b_ih_d  = (const float*)d_in[11];
  const float* b_hh_d  = (const float*)d_in[12];
  const float* W_out   = (const float*)d_in[13];
  const float* b_out   = (const float*)d_in[14];
  float* out = (float*)d_out;

  char* p = (char*)d_ws;
  auto take = [&](size_t n) { char* q = p; p += (n + 255) & ~(size_t)255; return q; };
  unsigned short* Wbf_e  = (unsigned short*)take((size_t)G3 * HID * 2);
  unsigned short* Wbf_1d = (unsigned short*)take((size_t)G3 * HID * 2);
  unsigned short* Wbf_2d = (unsigned short*)take((size_t)G3 * HID * 2);
  unsigned short* Wbf_o  = (unsigned short*)take((size_t)VOCAB * HID * 2);
  unsigned short* Wv_e   = (unsigned short*)take((size_t)G3 * HID * 2);
  unsigned short* Wv_d   = (unsigned short*)take((size_t)G3 * HID * 2);
  unsigned short* A_ed   = (unsigned short*)take((size_t)2048 * HID * 2);
  unsigned short* A_th   = (unsigned short*)take((size_t)128 * HID * 2);
  unsigned short* A_hs   = (unsigned short*)take((size_t)2048 * HID * 2);
  float* xpT = (float*)take((size_t)64 * 3 * NB * HID * 4);
  float* t2  = (float*)take((size_t)128 * G3 * 4);
  // hbf + bar contiguous, zeroed together: 2*NB*HID*2 bytes + 1024 bytes = 132096 B = 33024 f32
  unsigned short* hbf = (unsigned short*)take((size_t)2 * NB * HID * 2);
  int*   bar  = (int*)take(1024);
  float* hfin = (float*)take((size_t)NB * HID * 4);

  // weight converts (fp32 -> bf16)
  cvt_bf16<<<dim3((G3 * HID) / 1024), 256, 0, stream>>>(W_ih_e, Wbf_e);
  cvt_split_d<<<dim3(G3), 256, 0, stream>>>(W_ih_d, Wbf_1d, Wbf_2d);
  cvt_bf16<<<dim3((VOCAB * HID) / 1024), 256, 0, stream>>>(W_out, Wbf_o);
  cvt_whh<<<dim3(G3), 256, 0, stream>>>(W_hh_e, Wv_e);
  cvt_whh<<<dim3(G3), 256, 0, stream>>>(W_hh_d, Wv_d);

  // ---- encoder ----
  gather_embed<<<dim3(NB * SLEN), 256, 0, stream>>>(input_seqs, emb_enc, A_ed, 0);
  gemm_bf16<1, 16><<<dim3(384), 256, 0, stream>>>(A_ed, Wbf_e, b_ih_e, nullptr, xpT, G3);
  zero_f32<<<dim3(129), 256, 0, stream>>>((float*)hbf);   // hbf (128KB) + bar (1KB)
  gru_scan<<<dim3(64), 192, 0, stream>>>(Wv_e, b_hh_e, xpT, hbf, input_lens,
                                         nullptr, hfin, bar, SLEN);

  // ---- decoder pre ----
  gather_thought<<<dim3(128), 256, 0, stream>>>(hfin, A_th);
  gemm_bf16<0, 1><<<dim3(24), 256, 0, stream>>>(A_th, Wbf_2d, b_ih_d, nullptr, t2, G3);
  gather_embed<<<dim3(NB * TLEN), 256, 0, stream>>>(target_seqs, emb_dec, A_ed, 1);
  gemm_bf16<2, 16><<<dim3(384), 256, 0, stream>>>(A_ed, Wbf_1d, nullptr, t2, xpT, G3);

  // ---- decoder scan ----
  zero_f32<<<dim3(129), 256, 0, stream>>>((float*)hbf);
  gru_scan<<<dim3(64), 192, 0, stream>>>(Wv_d, b_hh_d, xpT, hbf, nullptr,
                                         A_hs, nullptr, bar, TLEN);

  // ---- logits (direct to d_out) + in-place log_softmax ----
  gemm_bf16<3, 16><<<dim3(4000), 256, 0, stream>>>(A_hs, Wbf_o, b_out, nullptr, out, VOCAB);
  log_softmax_rows<<<dim3(NB * TLEN), 256, 0, stream>>>(out);
}

// Round 3
// 2486.698 us; speedup vs baseline: 1.6309x; 1.2208x over previous
//
#include <hip/hip_runtime.h>
#include <stdint.h>
#include <stddef.h>

#define VOCAB 32000
#define HID   1024
#define NB    32
#define SLEN  64
#define TLEN  64
#define G3    3072

typedef float          f32x4  __attribute__((ext_vector_type(4)));
typedef __bf16         bf16x8 __attribute__((ext_vector_type(8)));
typedef unsigned short u16x8  __attribute__((ext_vector_type(8)));
typedef unsigned short u16x4  __attribute__((ext_vector_type(4)));
typedef unsigned int   u32x4  __attribute__((ext_vector_type(4)));

union BfPun { u16x8 u; bf16x8 b; };
union QPun  { unsigned long long q[2]; bf16x8 b; };

__device__ __forceinline__ unsigned short f2bf(float f) {
  unsigned int u = __builtin_bit_cast(unsigned int, f);
  u += 0x7FFFu + ((u >> 16) & 1u);   // RNE round to bf16
  return (unsigned short)(u >> 16);
}

// ---------------- converts / gathers / init ----------------

__global__ __launch_bounds__(256) void cvt_bf16(const float* __restrict__ in,
                                                unsigned short* __restrict__ out) {
  size_t idx = ((size_t)blockIdx.x * 256 + threadIdx.x) * 4;
  f32x4 v = *(const f32x4*)(in + idx);
  u16x4 o;
  o[0] = f2bf(v[0]); o[1] = f2bf(v[1]); o[2] = f2bf(v[2]); o[3] = f2bf(v[3]);
  *(u16x4*)(out + idx) = o;
}

// W_ih_d [3072][2048] -> W1 (cols 0..1023), W2 (cols 1024..2047), both bf16 [3072][1024]
__global__ __launch_bounds__(256) void cvt_split_d(const float* __restrict__ Wd,
                                                   unsigned short* __restrict__ W1,
                                                   unsigned short* __restrict__ W2) {
  int r = blockIdx.x, q = threadIdx.x;
  const float* src = Wd + (size_t)r * 2048;
  f32x4 v1 = *(const f32x4*)(src + q * 4);
  f32x4 v2 = *(const f32x4*)(src + 1024 + q * 4);
  u16x4 o1, o2;
  o1[0]=f2bf(v1[0]); o1[1]=f2bf(v1[1]); o1[2]=f2bf(v1[2]); o1[3]=f2bf(v1[3]);
  o2[0]=f2bf(v2[0]); o2[1]=f2bf(v2[1]); o2[2]=f2bf(v2[2]); o2[3]=f2bf(v2[3]);
  *(u16x4*)(W1 + (size_t)r * 1024 + q * 4) = o1;
  *(u16x4*)(W2 + (size_t)r * 1024 + q * 4) = o2;
}

// W_hh [3H][H] fp32 -> per-scan-block reordered bf16: Wv[blk][g*16+il][k]
__global__ __launch_bounds__(256) void cvt_whh(const float* __restrict__ W,
                                               unsigned short* __restrict__ Wv) {
  int r = blockIdx.x;              // 0..3071 original row
  int g = r >> 10, i = r & 1023;
  int blk = i >> 4, il = i & 15;
  size_t dst = ((size_t)blk * 48 + g * 16 + il) * HID;
  int q = threadIdx.x;
  f32x4 v = *(const f32x4*)(W + (size_t)r * HID + q * 4);
  u16x4 o;
  o[0]=f2bf(v[0]); o[1]=f2bf(v[1]); o[2]=f2bf(v[2]); o[3]=f2bf(v[3]);
  *(u16x4*)(Wv + dst + q * 4) = o;
}

__global__ __launch_bounds__(256) void gather_embed(const int* __restrict__ seqs,
                                                    const float* __restrict__ emb,
                                                    unsigned short* __restrict__ Aout,
                                                    int relu) {
  int r = blockIdx.x, q = threadIdx.x;
  int tok = seqs[r];
  f32x4 v = *(const f32x4*)(emb + (size_t)tok * HID + q * 4);
  if (relu) {
    v[0]=fmaxf(v[0],0.f); v[1]=fmaxf(v[1],0.f); v[2]=fmaxf(v[2],0.f); v[3]=fmaxf(v[3],0.f);
  }
  u16x4 o; o[0]=f2bf(v[0]); o[1]=f2bf(v[1]); o[2]=f2bf(v[2]); o[3]=f2bf(v[3]);
  *(u16x4*)(Aout + (size_t)r * HID + q * 4) = o;
}

// relu(thought) -> bf16, rows 32..127 zero-padded
__global__ __launch_bounds__(256) void gather_thought(const float* __restrict__ hfin,
                                                      unsigned short* __restrict__ Aout) {
  int r = blockIdx.x, q = threadIdx.x;
  u16x4 o = {0, 0, 0, 0};
  if (r < NB) {
    f32x4 v = *(const f32x4*)(hfin + (size_t)r * HID + q * 4);
    o[0]=f2bf(fmaxf(v[0],0.f)); o[1]=f2bf(fmaxf(v[1],0.f));
    o[2]=f2bf(fmaxf(v[2],0.f)); o[3]=f2bf(fmaxf(v[3],0.f));
  }
  *(u16x4*)(Aout + (size_t)r * HID + q * 4) = o;
}

__global__ __launch_bounds__(256) void zero_f32(float* __restrict__ p) {
  p[blockIdx.x * 256 + threadIdx.x] = 0.f;
}

// ---------------- bf16 MFMA GEMM: C = A[M,1024] * B[N,1024]^T (+ epilogue) ----------------
// 1-D grid; XCD-chunked swizzle + (MT x 4) supertile: bm fast inside 4-wide column groups.
template<int MODE, int MT>
__global__ __launch_bounds__(256) void gemm_bf16(const unsigned short* __restrict__ A,
                                                 const unsigned short* __restrict__ Bw,
                                                 const float* __restrict__ bias,
                                                 const float* __restrict__ add2,
                                                 float* __restrict__ out, int N) {
  __shared__ unsigned short Abuf[128 * 32];
  __shared__ unsigned short Bbuf[128 * 32];
  const int K = HID;
  int tid = threadIdx.x, lane = tid & 63, wid = tid >> 6;
  int nwg = gridDim.x;
  int u = (blockIdx.x & 7) * (nwg >> 3) + (blockIdx.x >> 3);
  int g = u / (MT * 4);
  int r_ = u - g * (MT * 4);
  int bm = r_ % MT;
  int bn = g * 4 + r_ / MT;
  int wrow = wid >> 1, wcol = wid & 1;
  f32x4 zero4 = {0.f, 0.f, 0.f, 0.f};
  f32x4 acc[4][4];
#pragma unroll
  for (int i = 0; i < 4; ++i)
#pragma unroll
    for (int j = 0; j < 4; ++j) acc[i][j] = zero4;

  int srow = tid >> 2, spart = tid & 3;
  const unsigned short* Ag = A + ((size_t)bm * 128 + srow) * K + spart * 8;
  const unsigned short* Bg = Bw + ((size_t)bn * 128 + srow) * K + spart * 8;
  unsigned short* As = Abuf + srow * 32 + spart * 8;
  unsigned short* Bs = Bbuf + srow * 32 + spart * 8;

  for (int ks = 0; ks < 32; ++ks) {
    int k0 = ks * 32;
    u32x4 a0 = *(const u32x4*)(Ag + k0);
    u32x4 a1 = *(const u32x4*)(Ag + (size_t)64 * K + k0);
    u32x4 b0 = *(const u32x4*)(Bg + k0);
    u32x4 b1 = *(const u32x4*)(Bg + (size_t)64 * K + k0);
    __syncthreads();
    *(u32x4*)As = a0;
    *(u32x4*)(As + 64 * 32) = a1;
    *(u32x4*)Bs = b0;
    *(u32x4*)(Bs + 64 * 32) = b1;
    __syncthreads();
    bf16x8 af[4], bfr[4];
#pragma unroll
    for (int mi = 0; mi < 4; ++mi) {
      BfPun tpun;
      tpun.u = *(const u16x8*)(Abuf + (wrow * 64 + mi * 16 + (lane & 15)) * 32 + (lane >> 4) * 8);
      af[mi] = tpun.b;
    }
#pragma unroll
    for (int ni = 0; ni < 4; ++ni) {
      BfPun tpun;
      tpun.u = *(const u16x8*)(Bbuf + (wcol * 64 + ni * 16 + (lane & 15)) * 32 + (lane >> 4) * 8);
      bfr[ni] = tpun.b;
    }
#pragma unroll
    for (int mi = 0; mi < 4; ++mi)
#pragma unroll
      for (int ni = 0; ni < 4; ++ni)
        acc[mi][ni] = __builtin_amdgcn_mfma_f32_16x16x32_bf16(af[mi], bfr[ni], acc[mi][ni], 0, 0, 0);
  }

#pragma unroll
  for (int mi = 0; mi < 4; ++mi) {
    int rb = bm * 128 + wrow * 64 + mi * 16 + ((lane >> 4) << 2);
#pragma unroll
    for (int ni = 0; ni < 4; ++ni) {
      int c = bn * 128 + wcol * 64 + ni * 16 + (lane & 15);
#pragma unroll
      for (int e = 0; e < 4; ++e) {
        int r = rb + e;
        float v = acc[mi][ni][e];
        if (MODE == 0) {
          out[(size_t)r * N + c] = v + bias[c];
        } else if (MODE == 1) {
          int t = r & 63, b = r >> 6;
          int gg = c >> 10, ci = c & 1023;
          out[(((size_t)t * 3 + gg) * NB + b) * HID + ci] = v + bias[c];
        } else if (MODE == 2) {
          int t = r & 63, b = r >> 6;
          int gg = c >> 10, ci = c & 1023;
          out[(((size_t)t * 3 + gg) * NB + b) * HID + ci] = v + add2[(size_t)b * G3 + c];
        } else {
          int b = r & 31, t = r >> 5;
          out[((size_t)b * TLEN + t) * VOCAB + c] = v + bias[c];
        }
      }
    }
  }
}

// ---------------- persistent GRU scan (MFMA, W_hh in registers) ----------------
// 64 blocks x 192 threads. Cross-block h exchange via agent-scope (sc0/sc1, L3-coherent)
// 8-byte atomic loads/stores -- NO threadfence / L2 flush anywhere.
// Barrier: per-step arrival counter, relaxed agent atomics only.

__global__ __launch_bounds__(192, 1) void gru_scan(
    const unsigned short* __restrict__ Wv,   // [64][48][1024] bf16
    const float* __restrict__ b_hh,
    const float* __restrict__ xpT,           // [T][3][NB][HID]
    unsigned short* __restrict__ hbf,        // [2][NB][HID] bf16 exchange
    const int* __restrict__ lens,            // null => no freeze (decoder)
    unsigned short* __restrict__ hs_out,     // null for encoder; [T*NB][HID] bf16
    float* __restrict__ hfin,                // final h fp32 (encoder) or null
    int* __restrict__ bar, int nsteps) {     // bar[t]: arrival counters, zeroed
  __shared__ float gh[48][33];
  __shared__ float h32[32][16];
  __shared__ unsigned short hstage[32][16];
  __shared__ float bhh_s[48];
  __shared__ int   lens_s[32];
  int tid = threadIdx.x, lane = tid & 63, w = tid >> 6;
  int blk = blockIdx.x, i0 = blk * 16;

  if (tid < 32) lens_s[tid] = lens ? lens[tid] : 0x7fffffff;
  if (tid >= 64 && tid < 112) {
    int q = tid - 64;
    bhh_s[q] = b_hh[(size_t)(q >> 4) * HID + i0 + (q & 15)];
  }
  for (int x = tid; x < 512; x += 192) h32[x >> 4][x & 15] = 0.f;

  // W_hh slice held in registers for the whole scan (128 VGPR of A-fragments)
  const unsigned short* Wb = Wv + ((size_t)blk * 48 + w * 16 + (lane & 15)) * HID + (lane >> 4) * 8;
  bf16x8 af[32];
#pragma unroll
  for (int ks = 0; ks < 32; ++ks) { BfPun t_; t_.u = *(const u16x8*)(Wb + ks * 32); af[ks] = t_.b; }
  __syncthreads();

  int rb0 = (lane & 15) * (HID / 4);          // u64 units per h row = 256
  int rb1 = rb0 + 16 * (HID / 4);
  int c0 = (lane >> 4) * 2;

  for (int t = 0; t < nsteps; ++t) {
    f32x4 acc0 = {0.f, 0.f, 0.f, 0.f}, acc1 = {0.f, 0.f, 0.f, 0.f};
    if (t > 0) {
      const unsigned long long* hb64 =
          (const unsigned long long*)(hbf + ((t & 1) ? (size_t)NB * HID : 0));
#pragma unroll
      for (int ks = 0; ks < 32; ++ks) {
        QPun q0, q1;
        q0.q[0] = __hip_atomic_load(hb64 + rb0 + ks * 8 + c0,     __ATOMIC_RELAXED, __HIP_MEMORY_SCOPE_AGENT);
        q0.q[1] = __hip_atomic_load(hb64 + rb0 + ks * 8 + c0 + 1, __ATOMIC_RELAXED, __HIP_MEMORY_SCOPE_AGENT);
        q1.q[0] = __hip_atomic_load(hb64 + rb1 + ks * 8 + c0,     __ATOMIC_RELAXED, __HIP_MEMORY_SCOPE_AGENT);
        q1.q[1] = __hip_atomic_load(hb64 + rb1 + ks * 8 + c0 + 1, __ATOMIC_RELAXED, __HIP_MEMORY_SCOPE_AGENT);
        acc0 = __builtin_amdgcn_mfma_f32_16x16x32_bf16(af[ks], q0.b, acc0, 0, 0, 0);
        acc1 = __builtin_amdgcn_mfma_f32_16x16x32_bf16(af[ks], q1.b, acc1, 0, 0, 0);
      }
    }
    int vr0 = w * 16 + (lane >> 4) * 4, cb = lane & 15;
#pragma unroll
    for (int e = 0; e < 4; ++e) {
      gh[vr0 + e][cb]      = acc0[e];
      gh[vr0 + e][16 + cb] = acc1[e];
    }
    __syncthreads();

    const float* xp_t = xpT + (size_t)t * 3 * NB * HID;
    for (int idx = tid; idx < 512; idx += 192) {
      int il = idx & 15, b = idx >> 4;
      float xr = xp_t[((size_t)0 * NB + b) * HID + i0 + il];
      float xz = xp_t[((size_t)1 * NB + b) * HID + i0 + il];
      float xn = xp_t[((size_t)2 * NB + b) * HID + i0 + il];
      float sr = gh[il][b], sz = gh[16 + il][b], sn = gh[32 + il][b];
      float rg = 1.f / (1.f + __expf(-(xr + sr + bhh_s[il])));
      float zg = 1.f / (1.f + __expf(-(xz + sz + bhh_s[16 + il])));
      float ng = tanhf(xn + rg * (sn + bhh_s[32 + il]));
      float hold = h32[b][il];
      float hnew = (1.f - zg) * ng + zg * hold;
      if (t >= lens_s[b]) hnew = hold;            // packed-seq freeze
      h32[b][il] = hnew;
      unsigned short hb16 = f2bf(hnew);
      hstage[b][il] = hb16;
      if (hs_out) hs_out[((size_t)t * NB + b) * HID + i0 + il] = hb16;
    }
    __syncthreads();

    unsigned short* hn = hbf + ((t & 1) ? 0 : (size_t)NB * HID);
    if (tid < 128) {
      int b = tid >> 2, part = tid & 3;
      unsigned long long v = 0;
#pragma unroll
      for (int e = 0; e < 4; ++e)
        v |= (unsigned long long)hstage[b][part * 4 + e] << (16 * e);
      __hip_atomic_store((unsigned long long*)(hn + (size_t)b * HID + i0 + part * 4), v,
                         __ATOMIC_RELAXED, __HIP_MEMORY_SCOPE_AGENT);
    }

    if (t + 1 < nsteps) {
      __syncthreads();   // drains vmcnt for all waves (stores visible at L3)
      if (tid == 0) {
        __hip_atomic_fetch_add(&bar[t], 1, __ATOMIC_RELAXED, __HIP_MEMORY_SCOPE_AGENT);
        while (__hip_atomic_load(&bar[t], __ATOMIC_RELAXED, __HIP_MEMORY_SCOPE_AGENT) < (int)gridDim.x)
          __builtin_amdgcn_s_sleep(1);
      }
      __syncthreads();
    }
  }

  if (hfin) {
    for (int idx = tid; idx < 512; idx += 192) {
      int il = idx & 15, b = idx >> 4;
      hfin[(size_t)b * HID + i0 + il] = h32[b][il];
    }
  }
}

// ---------------- in-place row log_softmax on d_out [2048 rows x 32000] ----------------
__global__ __launch_bounds__(256) void log_softmax_rows(float* __restrict__ out) {
  size_t row = blockIdx.x;
  float* p = out + row * VOCAB;
  f32x4* p4 = (f32x4*)p;
  int tid = threadIdx.x;
  float m = -3.0e38f, s = 0.f;
  for (int j = tid; j < VOCAB / 4; j += 256) {
    f32x4 v = p4[j];
#pragma unroll
    for (int e = 0; e < 4; ++e) {
      float x = v[e];
      float nm = fmaxf(m, x);
      s = s * __expf(m - nm) + __expf(x - nm);
      m = nm;
    }
  }
#pragma unroll
  for (int off = 1; off < 64; off <<= 1) {
    float m2 = __shfl_xor(m, off, 64);
    float s2 = __shfl_xor(s, off, 64);
    float nm = fmaxf(m, m2);
    s = s * __expf(m - nm) + s2 * __expf(m2 - nm);
    m = nm;
  }
  __shared__ float ms[4], ss[4];
  if ((tid & 63) == 0) { ms[tid >> 6] = m; ss[tid >> 6] = s; }
  __syncthreads();
  float M = fmaxf(fmaxf(ms[0], ms[1]), fmaxf(ms[2], ms[3]));
  float S = ss[0]*__expf(ms[0]-M) + ss[1]*__expf(ms[1]-M) +
            ss[2]*__expf(ms[2]-M) + ss[3]*__expf(ms[3]-M);
  float lse = M + __logf(S);
  for (int j = tid; j < VOCAB / 4; j += 256) {
    f32x4 v = p4[j];
    v[0] -= lse; v[1] -= lse; v[2] -= lse; v[3] -= lse;
    p4[j] = v;
  }
}

// ---------------- host ----------------

extern "C" void kernel_launch(void* const* d_in, const int* in_sizes, int n_in,
                              void* d_out, int out_size, void* d_ws, size_t ws_size,
                              hipStream_t stream) {
  (void)in_sizes; (void)n_in; (void)out_size; (void)ws_size;
  const int*   input_seqs  = (const int*)d_in[0];
  const int*   target_seqs = (const int*)d_in[1];
  const int*   input_lens  = (const int*)d_in[2];
  const float* emb_enc = (const float*)d_in[3];
  const float* W_ih_e  = (const float*)d_in[4];
  const float* W_hh_e  = (const float*)d_in[5];
  const float* b_ih_e  = (const float*)d_in[6];
  const float* b_hh_e  = (const float*)d_in[7];
  const float* emb_dec = (const float*)d_in[8];
  const float* W_ih_d  = (const float*)d_in[9];
  const float* W_hh_d  = (const float*)d_in[10];
  const float* b_ih_d  = (const float*)d_in[11];
  const float* b_hh_d  = (const float*)d_in[12];
  const float* W_out   = (const float*)d_in[13];
  const float* b_out   = (const float*)d_in[14];
  float* out = (float*)d_out;

  char* p = (char*)d_ws;
  auto take = [&](size_t n) { char* q = p; p += (n + 255) & ~(size_t)255; return q; };
  unsigned short* Wbf_e  = (unsigned short*)take((size_t)G3 * HID * 2);
  unsigned short* Wbf_1d = (unsigned short*)take((size_t)G3 * HID * 2);
  unsigned short* Wbf_2d = (unsigned short*)take((size_t)G3 * HID * 2);
  unsigned short* Wbf_o  = (unsigned short*)take((size_t)VOCAB * HID * 2);
  unsigned short* Wv_e   = (unsigned short*)take((size_t)G3 * HID * 2);
  unsigned short* Wv_d   = (unsigned short*)take((size_t)G3 * HID * 2);
  unsigned short* A_ed   = (unsigned short*)take((size_t)2048 * HID * 2);
  unsigned short* A_th   = (unsigned short*)take((size_t)128 * HID * 2);
  unsigned short* A_hs   = (unsigned short*)take((size_t)2048 * HID * 2);
  float* xpT = (float*)take((size_t)64 * 3 * NB * HID * 4);
  float* t2  = (float*)take((size_t)128 * G3 * 4);
  unsigned short* hbf = (unsigned short*)take((size_t)2 * NB * HID * 2);
  int*   bar  = (int*)take(1024);              // bar_enc[64] | bar_dec[64]
  float* hfin = (float*)take((size_t)NB * HID * 4);

  // weight converts (fp32 -> bf16)
  cvt_bf16<<<dim3((G3 * HID) / 1024), 256, 0, stream>>>(W_ih_e, Wbf_e);
  cvt_split_d<<<dim3(G3), 256, 0, stream>>>(W_ih_d, Wbf_1d, Wbf_2d);
  cvt_bf16<<<dim3((VOCAB * HID) / 1024), 256, 0, stream>>>(W_out, Wbf_o);
  cvt_whh<<<dim3(G3), 256, 0, stream>>>(W_hh_e, Wv_e);
  cvt_whh<<<dim3(G3), 256, 0, stream>>>(W_hh_d, Wv_d);
  zero_f32<<<dim3(1), 256, 0, stream>>>((float*)bar);   // both scans' barrier counters

  // ---- encoder ----
  gather_embed<<<dim3(NB * SLEN), 256, 0, stream>>>(input_seqs, emb_enc, A_ed, 0);
  gemm_bf16<1, 16><<<dim3(384), 256, 0, stream>>>(A_ed, Wbf_e, b_ih_e, nullptr, xpT, G3);
  gru_scan<<<dim3(64), 192, 0, stream>>>(Wv_e, b_hh_e, xpT, hbf, input_lens,
                                         nullptr, hfin, bar, SLEN);

  // ---- decoder pre ----
  gather_thought<<<dim3(128), 256, 0, stream>>>(hfin, A_th);
  gemm_bf16<0, 1><<<dim3(24), 256, 0, stream>>>(A_th, Wbf_2d, b_ih_d, nullptr, t2, G3);
  gather_embed<<<dim3(NB * TLEN), 256, 0, stream>>>(target_seqs, emb_dec, A_ed, 1);
  gemm_bf16<2, 16><<<dim3(384), 256, 0, stream>>>(A_ed, Wbf_1d, nullptr, t2, xpT, G3);

  // ---- decoder scan ----
  gru_scan<<<dim3(64), 192, 0, stream>>>(Wv_d, b_hh_d, xpT, hbf, nullptr,
                                         A_hs, nullptr, bar + 64, TLEN);

  // ---- logits (direct to d_out) + in-place log_softmax ----
  gemm_bf16<3, 16><<<dim3(4000), 256, 0, stream>>>(A_hs, Wbf_o, b_out, nullptr, out, VOCAB);
  log_softmax_rows<<<dim3(NB * TLEN), 256, 0, stream>>>(out);
}

// Round 4
// 1978.456 us; speedup vs baseline: 2.0499x; 1.2569x over previous
//
#include <hip/hip_runtime.h>
#include <stdint.h>
#include <stddef.h>

#define VOCAB 32000
#define HID   1024
#define NB    32
#define SLEN  64
#define TLEN  64
#define G3    3072

typedef float          f32x4  __attribute__((ext_vector_type(4)));
typedef __bf16         bf16x8 __attribute__((ext_vector_type(8)));
typedef unsigned short u16x8  __attribute__((ext_vector_type(8)));
typedef unsigned short u16x4  __attribute__((ext_vector_type(4)));
typedef unsigned int   u32x4  __attribute__((ext_vector_type(4)));

union BfPun { u16x8 u; bf16x8 b; };

__device__ __forceinline__ unsigned short f2bf(float f) {
  unsigned int u = __builtin_bit_cast(unsigned int, f);
  u += 0x7FFFu + ((u >> 16) & 1u);   // RNE round to bf16
  return (unsigned short)(u >> 16);
}

// ---------------- converts / gathers / init ----------------

__global__ __launch_bounds__(256) void cvt_bf16(const float* __restrict__ in,
                                                unsigned short* __restrict__ out) {
  size_t idx = ((size_t)blockIdx.x * 256 + threadIdx.x) * 4;
  f32x4 v = *(const f32x4*)(in + idx);
  u16x4 o;
  o[0] = f2bf(v[0]); o[1] = f2bf(v[1]); o[2] = f2bf(v[2]); o[3] = f2bf(v[3]);
  *(u16x4*)(out + idx) = o;
}

// W_ih_d [3072][2048] -> W1 (cols 0..1023), W2 (cols 1024..2047), both bf16 [3072][1024]
__global__ __launch_bounds__(256) void cvt_split_d(const float* __restrict__ Wd,
                                                   unsigned short* __restrict__ W1,
                                                   unsigned short* __restrict__ W2) {
  int r = blockIdx.x, q = threadIdx.x;
  const float* src = Wd + (size_t)r * 2048;
  f32x4 v1 = *(const f32x4*)(src + q * 4);
  f32x4 v2 = *(const f32x4*)(src + 1024 + q * 4);
  u16x4 o1, o2;
  o1[0]=f2bf(v1[0]); o1[1]=f2bf(v1[1]); o1[2]=f2bf(v1[2]); o1[3]=f2bf(v1[3]);
  o2[0]=f2bf(v2[0]); o2[1]=f2bf(v2[1]); o2[2]=f2bf(v2[2]); o2[3]=f2bf(v2[3]);
  *(u16x4*)(W1 + (size_t)r * 1024 + q * 4) = o1;
  *(u16x4*)(W2 + (size_t)r * 1024 + q * 4) = o2;
}

__global__ __launch_bounds__(256) void gather_embed(const int* __restrict__ seqs,
                                                    const float* __restrict__ emb,
                                                    unsigned short* __restrict__ Aout,
                                                    int relu) {
  int r = blockIdx.x, q = threadIdx.x;
  int tok = seqs[r];
  f32x4 v = *(const f32x4*)(emb + (size_t)tok * HID + q * 4);
  if (relu) {
    v[0]=fmaxf(v[0],0.f); v[1]=fmaxf(v[1],0.f); v[2]=fmaxf(v[2],0.f); v[3]=fmaxf(v[3],0.f);
  }
  u16x4 o; o[0]=f2bf(v[0]); o[1]=f2bf(v[1]); o[2]=f2bf(v[2]); o[3]=f2bf(v[3]);
  *(u16x4*)(Aout + (size_t)r * HID + q * 4) = o;
}

// relu(thought) -> bf16, rows 32..127 zero-padded
__global__ __launch_bounds__(256) void gather_thought(const float* __restrict__ hfin,
                                                      unsigned short* __restrict__ Aout) {
  int r = blockIdx.x, q = threadIdx.x;
  u16x4 o = {0, 0, 0, 0};
  if (r < NB) {
    f32x4 v = *(const f32x4*)(hfin + (size_t)r * HID + q * 4);
    o[0]=f2bf(fmaxf(v[0],0.f)); o[1]=f2bf(fmaxf(v[1],0.f));
    o[2]=f2bf(fmaxf(v[2],0.f)); o[3]=f2bf(fmaxf(v[3],0.f));
  }
  *(u16x4*)(Aout + (size_t)r * HID + q * 4) = o;
}

__global__ __launch_bounds__(256) void zero_f32(float* __restrict__ p) {
  p[blockIdx.x * 256 + threadIdx.x] = 0.f;
}

// ---------------- bf16 MFMA GEMM: C = A[M,1024] * B[N,1024]^T (+ epilogue) ----------------
// 1-D grid; XCD-chunked swizzle + (MT x 4) supertile: bm fast inside 4-wide column groups.
template<int MODE, int MT>
__global__ __launch_bounds__(256) void gemm_bf16(const unsigned short* __restrict__ A,
                                                 const unsigned short* __restrict__ Bw,
                                                 const float* __restrict__ bias,
                                                 const float* __restrict__ add2,
                                                 float* __restrict__ out, int N) {
  __shared__ unsigned short Abuf[128 * 32];
  __shared__ unsigned short Bbuf[128 * 32];
  const int K = HID;
  int tid = threadIdx.x, lane = tid & 63, wid = tid >> 6;
  int nwg = gridDim.x;
  int u = (blockIdx.x & 7) * (nwg >> 3) + (blockIdx.x >> 3);
  int g = u / (MT * 4);
  int r_ = u - g * (MT * 4);
  int bm = r_ % MT;
  int bn = g * 4 + r_ / MT;
  int wrow = wid >> 1, wcol = wid & 1;
  f32x4 zero4 = {0.f, 0.f, 0.f, 0.f};
  f32x4 acc[4][4];
#pragma unroll
  for (int i = 0; i < 4; ++i)
#pragma unroll
    for (int j = 0; j < 4; ++j) acc[i][j] = zero4;

  int srow = tid >> 2, spart = tid & 3;
  const unsigned short* Ag = A + ((size_t)bm * 128 + srow) * K + spart * 8;
  const unsigned short* Bg = Bw + ((size_t)bn * 128 + srow) * K + spart * 8;
  unsigned short* As = Abuf + srow * 32 + spart * 8;
  unsigned short* Bs = Bbuf + srow * 32 + spart * 8;

  for (int ks = 0; ks < 32; ++ks) {
    int k0 = ks * 32;
    u32x4 a0 = *(const u32x4*)(Ag + k0);
    u32x4 a1 = *(const u32x4*)(Ag + (size_t)64 * K + k0);
    u32x4 b0 = *(const u32x4*)(Bg + k0);
    u32x4 b1 = *(const u32x4*)(Bg + (size_t)64 * K + k0);
    __syncthreads();
    *(u32x4*)As = a0;
    *(u32x4*)(As + 64 * 32) = a1;
    *(u32x4*)Bs = b0;
    *(u32x4*)(Bs + 64 * 32) = b1;
    __syncthreads();
    bf16x8 af[4], bfr[4];
#pragma unroll
    for (int mi = 0; mi < 4; ++mi) {
      BfPun tpun;
      tpun.u = *(const u16x8*)(Abuf + (wrow * 64 + mi * 16 + (lane & 15)) * 32 + (lane >> 4) * 8);
      af[mi] = tpun.b;
    }
#pragma unroll
    for (int ni = 0; ni < 4; ++ni) {
      BfPun tpun;
      tpun.u = *(const u16x8*)(Bbuf + (wcol * 64 + ni * 16 + (lane & 15)) * 32 + (lane >> 4) * 8);
      bfr[ni] = tpun.b;
    }
#pragma unroll
    for (int mi = 0; mi < 4; ++mi)
#pragma unroll
      for (int ni = 0; ni < 4; ++ni)
        acc[mi][ni] = __builtin_amdgcn_mfma_f32_16x16x32_bf16(af[mi], bfr[ni], acc[mi][ni], 0, 0, 0);
  }

#pragma unroll
  for (int mi = 0; mi < 4; ++mi) {
    int rb = bm * 128 + wrow * 64 + mi * 16 + ((lane >> 4) << 2);
#pragma unroll
    for (int ni = 0; ni < 4; ++ni) {
      int c = bn * 128 + wcol * 64 + ni * 16 + (lane & 15);
#pragma unroll
      for (int e = 0; e < 4; ++e) {
        int r = rb + e;
        float v = acc[mi][ni][e];
        if (MODE == 0) {
          out[(size_t)r * N + c] = v + bias[c];
        } else if (MODE == 1) {
          int t = r & 63, b = r >> 6;
          int gg = c >> 10, ci = c & 1023;
          out[(((size_t)t * 3 + gg) * NB + b) * HID + ci] = v + bias[c];
        } else if (MODE == 2) {
          int t = r & 63, b = r >> 6;
          int gg = c >> 10, ci = c & 1023;
          out[(((size_t)t * 3 + gg) * NB + b) * HID + ci] = v + add2[(size_t)b * G3 + c];
        } else {
          int b = r & 31, t = r >> 5;
          out[((size_t)b * TLEN + t) * VOCAB + c] = v + bias[c];
        }
      }
    }
  }
}

// ---------------- persistent GRU scan (MFMA) ----------------
// 64 blocks x 192 threads. h exchange through WRITE-ONCE per-step buffers:
//   writes: sc0/sc1 (agent-scope) 8B stores -> visible at memory-side L3;
//   reads:  PLAIN dwordx4 loads (pipelinable) -- safe because each location is
//           written exactly once per launch and only read after the per-step
//           arrival counter (so no reader cache holds a pre-write copy), and
//           values are deterministic across graph replays.
// W_hh (bf16) A-fragments are re-streamed from L2 each step (plain loads).

__global__ __launch_bounds__(192, 1) void gru_scan(
    const unsigned short* __restrict__ Whh,  // [3*HID][HID] bf16
    const float* __restrict__ b_hh,
    const float* __restrict__ xpT,           // [T][3][NB][HID]
    unsigned short* __restrict__ hbx,        // [nsteps][NB][HID] bf16 write-once
    const int* __restrict__ lens,            // null => no freeze (decoder)
    unsigned short* __restrict__ hs_out,     // null for encoder; [T*NB][HID] bf16
    float* __restrict__ hfin,                // final h fp32 (encoder) or null
    int* __restrict__ bar, int nsteps) {     // bar[t]: arrival counters, zeroed
  __shared__ float gh[48][33];
  __shared__ float h32[32][16];
  __shared__ unsigned short hstage[32][16];
  __shared__ float bhh_s[48];
  __shared__ int   lens_s[32];
  int tid = threadIdx.x, lane = tid & 63, w = tid >> 6;
  int blk = blockIdx.x, i0 = blk * 16;

  if (tid < 32) lens_s[tid] = lens ? lens[tid] : 0x7fffffff;
  if (tid >= 64 && tid < 112) {
    int q = tid - 64;
    bhh_s[q] = b_hh[(size_t)(q >> 4) * HID + i0 + (q & 15)];
  }
  for (int x = tid; x < 512; x += 192) h32[x >> 4][x & 15] = 0.f;
  __syncthreads();

  // A-fragment base: wave w = gate w, rows i0..i0+15 of gate w
  const unsigned short* wp = Whh + ((size_t)w * HID + i0 + (lane & 15)) * HID + (lane >> 4) * 8;

  for (int t = 0; t < nsteps; ++t) {
    f32x4 acc0 = {0.f, 0.f, 0.f, 0.f}, acc1 = {0.f, 0.f, 0.f, 0.f};
    if (t > 0) {
      const unsigned short* hp = hbx + (size_t)(t - 1) * NB * HID
                                 + (size_t)(lane & 15) * HID + (lane >> 4) * 8;
      const unsigned short* hp2 = hp + (size_t)16 * HID;
#pragma unroll
      for (int ks = 0; ks < 32; ++ks) {
        BfPun a_, b0_, b1_;
        a_.u  = *(const u16x8*)(wp  + ks * 32);
        b0_.u = *(const u16x8*)(hp  + ks * 32);
        b1_.u = *(const u16x8*)(hp2 + ks * 32);
        acc0 = __builtin_amdgcn_mfma_f32_16x16x32_bf16(a_.b, b0_.b, acc0, 0, 0, 0);
        acc1 = __builtin_amdgcn_mfma_f32_16x16x32_bf16(a_.b, b1_.b, acc1, 0, 0, 0);
      }
    }
    int vr0 = w * 16 + (lane >> 4) * 4, cb = lane & 15;
#pragma unroll
    for (int e = 0; e < 4; ++e) {
      gh[vr0 + e][cb]      = acc0[e];
      gh[vr0 + e][16 + cb] = acc1[e];
    }
    __syncthreads();

    const float* xp_t = xpT + (size_t)t * 3 * NB * HID;
    for (int idx = tid; idx < 512; idx += 192) {
      int il = idx & 15, b = idx >> 4;
      float xr = xp_t[((size_t)0 * NB + b) * HID + i0 + il];
      float xz = xp_t[((size_t)1 * NB + b) * HID + i0 + il];
      float xn = xp_t[((size_t)2 * NB + b) * HID + i0 + il];
      float sr = gh[il][b], sz = gh[16 + il][b], sn = gh[32 + il][b];
      float rg = 1.f / (1.f + __expf(-(xr + sr + bhh_s[il])));
      float zg = 1.f / (1.f + __expf(-(xz + sz + bhh_s[16 + il])));
      float ng = tanhf(xn + rg * (sn + bhh_s[32 + il]));
      float hold = h32[b][il];
      float hnew = (1.f - zg) * ng + zg * hold;
      if (t >= lens_s[b]) hnew = hold;            // packed-seq freeze
      h32[b][il] = hnew;
      unsigned short hb16 = f2bf(hnew);
      hstage[b][il] = hb16;
      if (hs_out) hs_out[((size_t)t * NB + b) * HID + i0 + il] = hb16;
    }
    __syncthreads();

    unsigned short* hn = hbx + (size_t)t * NB * HID;
    if (tid < 128) {
      int b = tid >> 2, part = tid & 3;
      unsigned long long v = 0;
#pragma unroll
      for (int e = 0; e < 4; ++e)
        v |= (unsigned long long)hstage[b][part * 4 + e] << (16 * e);
      __hip_atomic_store((unsigned long long*)(hn + (size_t)b * HID + i0 + part * 4), v,
                         __ATOMIC_RELAXED, __HIP_MEMORY_SCOPE_AGENT);
    }

    if (t + 1 < nsteps) {
      __syncthreads();   // compiler emits vmcnt(0) drain before s_barrier
      if (tid == 0) {
        __hip_atomic_fetch_add(&bar[t], 1, __ATOMIC_RELAXED, __HIP_MEMORY_SCOPE_AGENT);
        while (__hip_atomic_load(&bar[t], __ATOMIC_RELAXED, __HIP_MEMORY_SCOPE_AGENT) < (int)gridDim.x)
          __builtin_amdgcn_s_sleep(1);
      }
      __syncthreads();   // orders all h reads of step t+1 after the poll
    }
  }

  if (hfin) {
    for (int idx = tid; idx < 512; idx += 192) {
      int il = idx & 15, b = idx >> 4;
      hfin[(size_t)b * HID + i0 + il] = h32[b][il];
    }
  }
}

// ---------------- in-place row log_softmax on d_out [2048 rows x 32000] ----------------
__global__ __launch_bounds__(256) void log_softmax_rows(float* __restrict__ out) {
  size_t row = blockIdx.x;
  float* p = out + row * VOCAB;
  f32x4* p4 = (f32x4*)p;
  int tid = threadIdx.x;
  float m = -3.0e38f, s = 0.f;
  for (int j = tid; j < VOCAB / 4; j += 256) {
    f32x4 v = p4[j];
#pragma unroll
    for (int e = 0; e < 4; ++e) {
      float x = v[e];
      float nm = fmaxf(m, x);
      s = s * __expf(m - nm) + __expf(x - nm);
      m = nm;
    }
  }
#pragma unroll
  for (int off = 1; off < 64; off <<= 1) {
    float m2 = __shfl_xor(m, off, 64);
    float s2 = __shfl_xor(s, off, 64);
    float nm = fmaxf(m, m2);
    s = s * __expf(m - nm) + s2 * __expf(m2 - nm);
    m = nm;
  }
  __shared__ float ms[4], ss[4];
  if ((tid & 63) == 0) { ms[tid >> 6] = m; ss[tid >> 6] = s; }
  __syncthreads();
  float M = fmaxf(fmaxf(ms[0], ms[1]), fmaxf(ms[2], ms[3]));
  float S = ss[0]*__expf(ms[0]-M) + ss[1]*__expf(ms[1]-M) +
            ss[2]*__expf(ms[2]-M) + ss[3]*__expf(ms[3]-M);
  float lse = M + __logf(S);
  for (int j = tid; j < VOCAB / 4; j += 256) {
    f32x4 v = p4[j];
    v[0] -= lse; v[1] -= lse; v[2] -= lse; v[3] -= lse;
    p4[j] = v;
  }
}

// ---------------- host ----------------

extern "C" void kernel_launch(void* const* d_in, const int* in_sizes, int n_in,
                              void* d_out, int out_size, void* d_ws, size_t ws_size,
                              hipStream_t stream) {
  (void)in_sizes; (void)n_in; (void)out_size; (void)ws_size;
  const int*   input_seqs  = (const int*)d_in[0];
  const int*   target_seqs = (const int*)d_in[1];
  const int*   input_lens  = (const int*)d_in[2];
  const float* emb_enc = (const float*)d_in[3];
  const float* W_ih_e  = (const float*)d_in[4];
  const float* W_hh_e  = (const float*)d_in[5];
  const float* b_ih_e  = (const float*)d_in[6];
  const float* b_hh_e  = (const float*)d_in[7];
  const float* emb_dec = (const float*)d_in[8];
  const float* W_ih_d  = (const float*)d_in[9];
  const float* W_hh_d  = (const float*)d_in[10];
  const float* b_ih_d  = (const float*)d_in[11];
  const float* b_hh_d  = (const float*)d_in[12];
  const float* W_out   = (const float*)d_in[13];
  const float* b_out   = (const float*)d_in[14];
  float* out = (float*)d_out;

  char* p = (char*)d_ws;
  auto take = [&](size_t n) { char* q = p; p += (n + 255) & ~(size_t)255; return q; };
  unsigned short* Wbf_e  = (unsigned short*)take((size_t)G3 * HID * 2);
  unsigned short* Wbf_1d = (unsigned short*)take((size_t)G3 * HID * 2);
  unsigned short* Wbf_2d = (unsigned short*)take((size_t)G3 * HID * 2);
  unsigned short* Wbf_o  = (unsigned short*)take((size_t)VOCAB * HID * 2);
  unsigned short* Whh_eb = (unsigned short*)take((size_t)G3 * HID * 2);
  unsigned short* Whh_db = (unsigned short*)take((size_t)G3 * HID * 2);
  unsigned short* A_ed   = (unsigned short*)take((size_t)2048 * HID * 2);
  unsigned short* A_th   = (unsigned short*)take((size_t)128 * HID * 2);
  unsigned short* A_hs   = (unsigned short*)take((size_t)2048 * HID * 2);
  float* xpT = (float*)take((size_t)64 * 3 * NB * HID * 4);
  float* t2  = (float*)take((size_t)128 * G3 * 4);
  unsigned short* hbx_e = (unsigned short*)take((size_t)SLEN * NB * HID * 2);  // write-once enc
  unsigned short* hbx_d = (unsigned short*)take((size_t)TLEN * NB * HID * 2);  // write-once dec
  int*   bar  = (int*)take(1024);              // bar_enc[64] | bar_dec[64]
  float* hfin = (float*)take((size_t)NB * HID * 4);

  // weight converts (fp32 -> bf16)
  cvt_bf16<<<dim3((G3 * HID) / 1024), 256, 0, stream>>>(W_ih_e, Wbf_e);
  cvt_split_d<<<dim3(G3), 256, 0, stream>>>(W_ih_d, Wbf_1d, Wbf_2d);
  cvt_bf16<<<dim3((VOCAB * HID) / 1024), 256, 0, stream>>>(W_out, Wbf_o);
  cvt_bf16<<<dim3((G3 * HID) / 1024), 256, 0, stream>>>(W_hh_e, Whh_eb);
  cvt_bf16<<<dim3((G3 * HID) / 1024), 256, 0, stream>>>(W_hh_d, Whh_db);
  zero_f32<<<dim3(1), 256, 0, stream>>>((float*)bar);   // both scans' barrier counters

  // ---- encoder ----
  gather_embed<<<dim3(NB * SLEN), 256, 0, stream>>>(input_seqs, emb_enc, A_ed, 0);
  gemm_bf16<1, 16><<<dim3(384), 256, 0, stream>>>(A_ed, Wbf_e, b_ih_e, nullptr, xpT, G3);
  gru_scan<<<dim3(64), 192, 0, stream>>>(Whh_eb, b_hh_e, xpT, hbx_e, input_lens,
                                         nullptr, hfin, bar, SLEN);

  // ---- decoder pre ----
  gather_thought<<<dim3(128), 256, 0, stream>>>(hfin, A_th);
  gemm_bf16<0, 1><<<dim3(24), 256, 0, stream>>>(A_th, Wbf_2d, b_ih_d, nullptr, t2, G3);
  gather_embed<<<dim3(NB * TLEN), 256, 0, stream>>>(target_seqs, emb_dec, A_ed, 1);
  gemm_bf16<2, 16><<<dim3(384), 256, 0, stream>>>(A_ed, Wbf_1d, nullptr, t2, xpT, G3);

  // ---- decoder scan ----
  gru_scan<<<dim3(64), 192, 0, stream>>>(Whh_db, b_hh_d, xpT, hbx_d, nullptr,
                                         A_hs, nullptr, bar + 64, TLEN);

  // ---- logits (direct to d_out) + in-place log_softmax ----
  gemm_bf16<3, 16><<<dim3(4000), 256, 0, stream>>>(A_hs, Wbf_o, b_out, nullptr, out, VOCAB);
  log_softmax_rows<<<dim3(NB * TLEN), 256, 0, stream>>>(out);
}

// Round 5
// 1025.050 us; speedup vs baseline: 3.9565x; 1.9301x over previous
//
#include <hip/hip_runtime.h>
#include <stdint.h>
#include <stddef.h>

#define VOCAB 32000
#define HID   1024
#define NB    32
#define SLEN  64
#define TLEN  64
#define G3    3072

typedef float          f32x4  __attribute__((ext_vector_type(4)));
typedef float          f32x2  __attribute__((ext_vector_type(2)));
typedef __bf16         bf16x8 __attribute__((ext_vector_type(8)));
typedef unsigned short u16x8  __attribute__((ext_vector_type(8)));
typedef unsigned short u16x4  __attribute__((ext_vector_type(4)));
typedef unsigned int   u32x4  __attribute__((ext_vector_type(4)));

union BfPun { u16x8 u; bf16x8 b; };
union CvPun { u32x4 u; bf16x8 b; };

__device__ __forceinline__ unsigned short f2bf(float f) {
  unsigned int u = __builtin_bit_cast(unsigned int, f);
  u += 0x7FFFu + ((u >> 16) & 1u);   // RNE round to bf16
  return (unsigned short)(u >> 16);
}

// ---------------- converts / gathers / init ----------------

__global__ __launch_bounds__(256) void cvt_bf16(const float* __restrict__ in,
                                                unsigned short* __restrict__ out) {
  size_t idx = ((size_t)blockIdx.x * 256 + threadIdx.x) * 4;
  f32x4 v = *(const f32x4*)(in + idx);
  u16x4 o;
  o[0] = f2bf(v[0]); o[1] = f2bf(v[1]); o[2] = f2bf(v[2]); o[3] = f2bf(v[3]);
  *(u16x4*)(out + idx) = o;
}

// W_ih_d [3072][2048] -> W1 (cols 0..1023), W2 (cols 1024..2047), both bf16 [3072][1024]
__global__ __launch_bounds__(256) void cvt_split_d(const float* __restrict__ Wd,
                                                   unsigned short* __restrict__ W1,
                                                   unsigned short* __restrict__ W2) {
  int r = blockIdx.x, q = threadIdx.x;
  const float* src = Wd + (size_t)r * 2048;
  f32x4 v1 = *(const f32x4*)(src + q * 4);
  f32x4 v2 = *(const f32x4*)(src + 1024 + q * 4);
  u16x4 o1, o2;
  o1[0]=f2bf(v1[0]); o1[1]=f2bf(v1[1]); o1[2]=f2bf(v1[2]); o1[3]=f2bf(v1[3]);
  o2[0]=f2bf(v2[0]); o2[1]=f2bf(v2[1]); o2[2]=f2bf(v2[2]); o2[3]=f2bf(v2[3]);
  *(u16x4*)(W1 + (size_t)r * 1024 + q * 4) = o1;
  *(u16x4*)(W2 + (size_t)r * 1024 + q * 4) = o2;
}

// W_hh [3H][H] fp32 -> fragment-linear bf16: Wv[blk][g][ks][lane][8]
// value = W_hh[g*H + blk*16 + (lane&15)][ks*32 + (lane>>4)*8 + e]
__global__ __launch_bounds__(128) void cvt_whh_frag(const float* __restrict__ W,
                                                    unsigned short* __restrict__ Wv) {
  int r = blockIdx.x;              // 0..3071
  int g = r >> 10, i = r & 1023, blk = i >> 4, il = i & 15;
  int q = threadIdx.x;             // 8-elem chunk 0..127
  int ks = q >> 2, ksub = q & 3, lane = il + ksub * 16;
  f32x4 v0 = *(const f32x4*)(W + (size_t)r * HID + q * 8);
  f32x4 v1 = *(const f32x4*)(W + (size_t)r * HID + q * 8 + 4);
  u16x8 o;
  o[0]=f2bf(v0[0]); o[1]=f2bf(v0[1]); o[2]=f2bf(v0[2]); o[3]=f2bf(v0[3]);
  o[4]=f2bf(v1[0]); o[5]=f2bf(v1[1]); o[6]=f2bf(v1[2]); o[7]=f2bf(v1[3]);
  size_t dst = ((((size_t)blk * 3 + g) * 32 + ks) * 64 + lane) * 8;
  *(u16x8*)(Wv + dst) = o;
}

__global__ __launch_bounds__(256) void gather_embed(const int* __restrict__ seqs,
                                                    const float* __restrict__ emb,
                                                    unsigned short* __restrict__ Aout,
                                                    int relu) {
  int r = blockIdx.x, q = threadIdx.x;
  int tok = seqs[r];
  f32x4 v = *(const f32x4*)(emb + (size_t)tok * HID + q * 4);
  if (relu) {
    v[0]=fmaxf(v[0],0.f); v[1]=fmaxf(v[1],0.f); v[2]=fmaxf(v[2],0.f); v[3]=fmaxf(v[3],0.f);
  }
  u16x4 o; o[0]=f2bf(v[0]); o[1]=f2bf(v[1]); o[2]=f2bf(v[2]); o[3]=f2bf(v[3]);
  *(u16x4*)(Aout + (size_t)r * HID + q * 4) = o;
}

// relu(thought) -> bf16, rows 32..127 zero-padded
__global__ __launch_bounds__(256) void gather_thought(const float* __restrict__ hfin,
                                                      unsigned short* __restrict__ Aout) {
  int r = blockIdx.x, q = threadIdx.x;
  u16x4 o = {0, 0, 0, 0};
  if (r < NB) {
    f32x4 v = *(const f32x4*)(hfin + (size_t)r * HID + q * 4);
    o[0]=f2bf(fmaxf(v[0],0.f)); o[1]=f2bf(fmaxf(v[1],0.f));
    o[2]=f2bf(fmaxf(v[2],0.f)); o[3]=f2bf(fmaxf(v[3],0.f));
  }
  *(u16x4*)(Aout + (size_t)r * HID + q * 4) = o;
}

__global__ __launch_bounds__(256) void zero_f32(float* __restrict__ p) {
  p[blockIdx.x * 256 + threadIdx.x] = 0.f;
}

// ---------------- bf16 MFMA GEMM: C = A[M,1024] * B[N,1024]^T (+ epilogue) ----------------
template<int MODE, int MT>
__global__ __launch_bounds__(256) void gemm_bf16(const unsigned short* __restrict__ A,
                                                 const unsigned short* __restrict__ Bw,
                                                 const float* __restrict__ bias,
                                                 const float* __restrict__ add2,
                                                 float* __restrict__ out, int N) {
  __shared__ unsigned short Abuf[128 * 32];
  __shared__ unsigned short Bbuf[128 * 32];
  const int K = HID;
  int tid = threadIdx.x, lane = tid & 63, wid = tid >> 6;
  int nwg = gridDim.x;
  int u = (blockIdx.x & 7) * (nwg >> 3) + (blockIdx.x >> 3);
  int g = u / (MT * 4);
  int r_ = u - g * (MT * 4);
  int bm = r_ % MT;
  int bn = g * 4 + r_ / MT;
  int wrow = wid >> 1, wcol = wid & 1;
  f32x4 zero4 = {0.f, 0.f, 0.f, 0.f};
  f32x4 acc[4][4];
#pragma unroll
  for (int i = 0; i < 4; ++i)
#pragma unroll
    for (int j = 0; j < 4; ++j) acc[i][j] = zero4;

  int srow = tid >> 2, spart = tid & 3;
  const unsigned short* Ag = A + ((size_t)bm * 128 + srow) * K + spart * 8;
  const unsigned short* Bg = Bw + ((size_t)bn * 128 + srow) * K + spart * 8;
  unsigned short* As = Abuf + srow * 32 + spart * 8;
  unsigned short* Bs = Bbuf + srow * 32 + spart * 8;

  for (int ks = 0; ks < 32; ++ks) {
    int k0 = ks * 32;
    u32x4 a0 = *(const u32x4*)(Ag + k0);
    u32x4 a1 = *(const u32x4*)(Ag + (size_t)64 * K + k0);
    u32x4 b0 = *(const u32x4*)(Bg + k0);
    u32x4 b1 = *(const u32x4*)(Bg + (size_t)64 * K + k0);
    __syncthreads();
    *(u32x4*)As = a0;
    *(u32x4*)(As + 64 * 32) = a1;
    *(u32x4*)Bs = b0;
    *(u32x4*)(Bs + 64 * 32) = b1;
    __syncthreads();
    bf16x8 af[4], bfr[4];
#pragma unroll
    for (int mi = 0; mi < 4; ++mi) {
      BfPun tpun;
      tpun.u = *(const u16x8*)(Abuf + (wrow * 64 + mi * 16 + (lane & 15)) * 32 + (lane >> 4) * 8);
      af[mi] = tpun.b;
    }
#pragma unroll
    for (int ni = 0; ni < 4; ++ni) {
      BfPun tpun;
      tpun.u = *(const u16x8*)(Bbuf + (wcol * 64 + ni * 16 + (lane & 15)) * 32 + (lane >> 4) * 8);
      bfr[ni] = tpun.b;
    }
#pragma unroll
    for (int mi = 0; mi < 4; ++mi)
#pragma unroll
      for (int ni = 0; ni < 4; ++ni)
        acc[mi][ni] = __builtin_amdgcn_mfma_f32_16x16x32_bf16(af[mi], bfr[ni], acc[mi][ni], 0, 0, 0);
  }

#pragma unroll
  for (int mi = 0; mi < 4; ++mi) {
    int rb = bm * 128 + wrow * 64 + mi * 16 + ((lane >> 4) << 2);
#pragma unroll
    for (int ni = 0; ni < 4; ++ni) {
      int c = bn * 128 + wcol * 64 + ni * 16 + (lane & 15);
#pragma unroll
      for (int e = 0; e < 4; ++e) {
        int r = rb + e;
        float v = acc[mi][ni][e];
        if (MODE == 0) {
          out[(size_t)r * N + c] = v + bias[c];
        } else if (MODE == 1) {
          int t = r & 63, b = r >> 6;
          int gg = c >> 10, ci = c & 1023;
          out[(((size_t)t * 3 + gg) * NB + b) * HID + ci] = v + bias[c];
        } else if (MODE == 2) {
          int t = r & 63, b = r >> 6;
          int gg = c >> 10, ci = c & 1023;
          out[(((size_t)t * 3 + gg) * NB + b) * HID + ci] = v + add2[(size_t)b * G3 + c];
        } else {
          int b = r & 31, t = r >> 5;
          out[((size_t)b * TLEN + t) * VOCAB + c] = v + bias[c];
        }
      }
    }
  }
}

// ---------------- persistent GRU scan (MFMA, fragment-linear layouts) ----------------
// 64 blocks x 384 threads (6 waves = 3 gates x 2 batch-halves).
// W_hh slice (96KB, fragment-linear) staged in LDS once; per step the h B-frags
// are read as COALESCED 1KB global loads (write-once fragment-order buffers)
// through a depth-8 register prefetch pipeline. h stores are 4B agent-scope
// write-through; cross-block sync = per-step arrival counter (no fences).

__global__ __launch_bounds__(384, 1) void gru_scan(
    const unsigned short* __restrict__ Wv,   // [64][3][32][64][8] bf16
    const float* __restrict__ b_hh,
    const float* __restrict__ xpT,           // [T][3][NB][HID]
    unsigned short* __restrict__ hbx,        // [nsteps][2][32][64][8] write-once
    const int* __restrict__ lens,            // null => no freeze (decoder)
    unsigned short* __restrict__ hs_out,     // null for encoder; [T*NB][HID] bf16
    float* __restrict__ hfin,                // final h fp32 (encoder) or null
    int* __restrict__ bar, int nsteps) {     // bar[t]: arrival counters, zeroed
  __shared__ unsigned short Wlds[49152];     // 96 KB
  __shared__ float gh[48][33];
  __shared__ float h32[32][16];
  __shared__ float bhh_s[48];
  __shared__ int   lens_s[32];
  int tid = threadIdx.x, lane = tid & 63, w = tid >> 6;
  int g = w >> 1, part = w & 1;
  int blk = blockIdx.x, i0 = blk * 16;

  if (tid < 32) lens_s[tid] = lens ? lens[tid] : 0x7fffffff;
  if (tid >= 64 && tid < 112) {
    int q = tid - 64;
    bhh_s[q] = b_hh[(size_t)(q >> 4) * HID + i0 + (q & 15)];
  }
  if (tid < 256) h32[tid >> 3][((tid & 7) * 2)] = 0.f;
  if (tid < 256) h32[tid >> 3][((tid & 7) * 2) + 1] = 0.f;

  // stage W fragment slice into LDS (one time)
  {
    const unsigned short* Wsrc = Wv + (size_t)blk * 49152;
    for (int j = tid; j < 6144; j += 384)
      *(u16x8*)(Wlds + (size_t)j * 8) = *(const u16x8*)(Wsrc + (size_t)j * 8);
  }
  __syncthreads();

  // epilogue mapping (tid < 256): b = tid>>3, il pair = (tid&7)*2
  int eb = tid >> 3, eil = (tid & 7) * 2;
  // xp prefetch registers (for step t, loaded during step t-1)
  f32x2 xr2 = {0.f, 0.f}, xz2 = {0.f, 0.f}, xn2 = {0.f, 0.f};
  if (tid < 256) {
    const float* xb = xpT + (size_t)eb * HID + i0 + eil;
    xr2 = *(const f32x2*)(xb);
    xz2 = *(const f32x2*)(xb + (size_t)NB * HID);
    xn2 = *(const f32x2*)(xb + (size_t)2 * NB * HID);
  }

  for (int t = 0; t < nsteps; ++t) {
    f32x4 acc = {0.f, 0.f, 0.f, 0.f};
    if (t > 0) {
      // coalesced fragment loads of h(t-1), depth-8 register prefetch
      const unsigned short* hp = hbx + (size_t)(t - 1) * 32768 + part * 16384 + lane * 8;
      u32x4 pb[8];
#pragma unroll
      for (int j = 0; j < 8; ++j) pb[j] = *(const u32x4*)(hp + (size_t)j * 512);
#pragma unroll
      for (int ks = 0; ks < 32; ++ks) {
        BfPun a_;
        a_.u = *(const u16x8*)(Wlds + ((size_t)(g * 32 + ks) * 64 + lane) * 8);
        CvPun cv; cv.u = pb[ks & 7];
        if (ks + 8 < 32) pb[ks & 7] = *(const u32x4*)(hp + (size_t)(ks + 8) * 512);
        acc = __builtin_amdgcn_mfma_f32_16x16x32_bf16(a_.b, cv.b, acc, 0, 0, 0);
      }
    }
    {
      int il4 = (lane >> 4) * 4, cb = part * 16 + (lane & 15);
#pragma unroll
      for (int e = 0; e < 4; ++e) gh[g * 16 + il4 + e][cb] = acc[e];
    }
    __syncthreads();

    if (tid < 256) {
      float sr0 = gh[eil][eb],      sr1 = gh[eil + 1][eb];
      float sz0 = gh[16 + eil][eb], sz1 = gh[16 + eil + 1][eb];
      float sn0 = gh[32 + eil][eb], sn1 = gh[32 + eil + 1][eb];
      float rg0 = 1.f / (1.f + __expf(-(xr2[0] + sr0 + bhh_s[eil])));
      float rg1 = 1.f / (1.f + __expf(-(xr2[1] + sr1 + bhh_s[eil + 1])));
      float zg0 = 1.f / (1.f + __expf(-(xz2[0] + sz0 + bhh_s[16 + eil])));
      float zg1 = 1.f / (1.f + __expf(-(xz2[1] + sz1 + bhh_s[16 + eil + 1])));
      float ng0 = tanhf(xn2[0] + rg0 * (sn0 + bhh_s[32 + eil]));
      float ng1 = tanhf(xn2[1] + rg1 * (sn1 + bhh_s[32 + eil + 1]));
      float h0o = h32[eb][eil], h1o = h32[eb][eil + 1];
      float hn0 = (1.f - zg0) * ng0 + zg0 * h0o;
      float hn1 = (1.f - zg1) * ng1 + zg1 * h1o;
      if (t >= lens_s[eb]) { hn0 = h0o; hn1 = h1o; }   // packed-seq freeze
      h32[eb][eil] = hn0; h32[eb][eil + 1] = hn1;
      unsigned int pk = (unsigned int)f2bf(hn0) | ((unsigned int)f2bf(hn1) << 16);
      // fragment-order store: k = i0+eil
      int k = i0 + eil;
      int ksf = k >> 5, lnf = (eb & 15) + ((k >> 3) & 3) * 16, sub = k & 7;
      unsigned short* dst = hbx + (size_t)t * 32768 + (size_t)(eb >> 4) * 16384
                            + (size_t)ksf * 512 + lnf * 8 + sub;
      __hip_atomic_store((unsigned int*)dst, pk, __ATOMIC_RELAXED, __HIP_MEMORY_SCOPE_AGENT);
      if (hs_out)
        *(unsigned int*)(hs_out + ((size_t)t * NB + eb) * HID + k) = pk;
      // prefetch xp for t+1
      if (t + 1 < nsteps) {
        const float* xb = xpT + ((size_t)(t + 1) * 3 * NB + eb) * HID + i0 + eil;
        xr2 = *(const f32x2*)(xb);
        xz2 = *(const f32x2*)(xb + (size_t)NB * HID);
        xn2 = *(const f32x2*)(xb + (size_t)2 * NB * HID);
      }
    }

    if (t + 1 < nsteps) {
      __syncthreads();   // vmcnt(0) drain: hbx stores visible at L3
      if (tid == 0) {
        __hip_atomic_fetch_add(&bar[t], 1, __ATOMIC_RELAXED, __HIP_MEMORY_SCOPE_AGENT);
        while (__hip_atomic_load(&bar[t], __ATOMIC_RELAXED, __HIP_MEMORY_SCOPE_AGENT) < (int)gridDim.x)
          __builtin_amdgcn_s_sleep(1);
      }
      __syncthreads();
    }
  }

  if (hfin && tid < 256) {
    f32x2 hv; hv[0] = h32[eb][eil]; hv[1] = h32[eb][eil + 1];
    *(f32x2*)(hfin + (size_t)eb * HID + i0 + eil) = hv;
  }
}

// ---------------- in-place row log_softmax on d_out [2048 rows x 32000] ----------------
__global__ __launch_bounds__(256) void log_softmax_rows(float* __restrict__ out) {
  size_t row = blockIdx.x;
  float* p = out + row * VOCAB;
  f32x4* p4 = (f32x4*)p;
  int tid = threadIdx.x;
  float m = -3.0e38f, s = 0.f;
  for (int j = tid; j < VOCAB / 4; j += 256) {
    f32x4 v = p4[j];
#pragma unroll
    for (int e = 0; e < 4; ++e) {
      float x = v[e];
      float nm = fmaxf(m, x);
      s = s * __expf(m - nm) + __expf(x - nm);
      m = nm;
    }
  }
#pragma unroll
  for (int off = 1; off < 64; off <<= 1) {
    float m2 = __shfl_xor(m, off, 64);
    float s2 = __shfl_xor(s, off, 64);
    float nm = fmaxf(m, m2);
    s = s * __expf(m - nm) + s2 * __expf(m2 - nm);
    m = nm;
  }
  __shared__ float ms[4], ss[4];
  if ((tid & 63) == 0) { ms[tid >> 6] = m; ss[tid >> 6] = s; }
  __syncthreads();
  float M = fmaxf(fmaxf(ms[0], ms[1]), fmaxf(ms[2], ms[3]));
  float S = ss[0]*__expf(ms[0]-M) + ss[1]*__expf(ms[1]-M) +
            ss[2]*__expf(ms[2]-M) + ss[3]*__expf(ms[3]-M);
  float lse = M + __logf(S);
  for (int j = tid; j < VOCAB / 4; j += 256) {
    f32x4 v = p4[j];
    v[0] -= lse; v[1] -= lse; v[2] -= lse; v[3] -= lse;
    p4[j] = v;
  }
}

// ---------------- host ----------------

extern "C" void kernel_launch(void* const* d_in, const int* in_sizes, int n_in,
                              void* d_out, int out_size, void* d_ws, size_t ws_size,
                              hipStream_t stream) {
  (void)in_sizes; (void)n_in; (void)out_size; (void)ws_size;
  const int*   input_seqs  = (const int*)d_in[0];
  const int*   target_seqs = (const int*)d_in[1];
  const int*   input_lens  = (const int*)d_in[2];
  const float* emb_enc = (const float*)d_in[3];
  const float* W_ih_e  = (const float*)d_in[4];
  const float* W_hh_e  = (const float*)d_in[5];
  const float* b_ih_e  = (const float*)d_in[6];
  const float* b_hh_e  = (const float*)d_in[7];
  const float* emb_dec = (const float*)d_in[8];
  const float* W_ih_d  = (const float*)d_in[9];
  const float* W_hh_d  = (const float*)d_in[10];
  const float* b_ih_d  = (const float*)d_in[11];
  const float* b_hh_d  = (const float*)d_in[12];
  const float* W_out   = (const float*)d_in[13];
  const float* b_out   = (const float*)d_in[14];
  float* out = (float*)d_out;

  char* p = (char*)d_ws;
  auto take = [&](size_t n) { char* q = p; p += (n + 255) & ~(size_t)255; return q; };
  unsigned short* Wbf_e  = (unsigned short*)take((size_t)G3 * HID * 2);
  unsigned short* Wbf_1d = (unsigned short*)take((size_t)G3 * HID * 2);
  unsigned short* Wbf_2d = (unsigned short*)take((size_t)G3 * HID * 2);
  unsigned short* Wbf_o  = (unsigned short*)take((size_t)VOCAB * HID * 2);
  unsigned short* Wv_e   = (unsigned short*)take((size_t)G3 * HID * 2);
  unsigned short* Wv_d   = (unsigned short*)take((size_t)G3 * HID * 2);
  unsigned short* A_ed   = (unsigned short*)take((size_t)2048 * HID * 2);
  unsigned short* A_th   = (unsigned short*)take((size_t)128 * HID * 2);
  unsigned short* A_hs   = (unsigned short*)take((size_t)2048 * HID * 2);
  float* xpT = (float*)take((size_t)64 * 3 * NB * HID * 4);
  float* t2  = (float*)take((size_t)128 * G3 * 4);
  unsigned short* hbx_e = (unsigned short*)take((size_t)SLEN * NB * HID * 2);
  unsigned short* hbx_d = (unsigned short*)take((size_t)TLEN * NB * HID * 2);
  int*   bar  = (int*)take(1024);              // bar_enc[64] | bar_dec[64]
  float* hfin = (float*)take((size_t)NB * HID * 4);

  // weight converts (fp32 -> bf16)
  cvt_bf16<<<dim3((G3 * HID) / 1024), 256, 0, stream>>>(W_ih_e, Wbf_e);
  cvt_split_d<<<dim3(G3), 256, 0, stream>>>(W_ih_d, Wbf_1d, Wbf_2d);
  cvt_bf16<<<dim3((VOCAB * HID) / 1024), 256, 0, stream>>>(W_out, Wbf_o);
  cvt_whh_frag<<<dim3(G3), 128, 0, stream>>>(W_hh_e, Wv_e);
  cvt_whh_frag<<<dim3(G3), 128, 0, stream>>>(W_hh_d, Wv_d);
  zero_f32<<<dim3(1), 256, 0, stream>>>((float*)bar);   // both scans' barrier counters

  // ---- encoder ----
  gather_embed<<<dim3(NB * SLEN), 256, 0, stream>>>(input_seqs, emb_enc, A_ed, 0);
  gemm_bf16<1, 16><<<dim3(384), 256, 0, stream>>>(A_ed, Wbf_e, b_ih_e, nullptr, xpT, G3);
  gru_scan<<<dim3(64), 384, 0, stream>>>(Wv_e, b_hh_e, xpT, hbx_e, input_lens,
                                         nullptr, hfin, bar, SLEN);

  // ---- decoder pre ----
  gather_thought<<<dim3(128), 256, 0, stream>>>(hfin, A_th);
  gemm_bf16<0, 1><<<dim3(24), 256, 0, stream>>>(A_th, Wbf_2d, b_ih_d, nullptr, t2, G3);
  gather_embed<<<dim3(NB * TLEN), 256, 0, stream>>>(target_seqs, emb_dec, A_ed, 1);
  gemm_bf16<2, 16><<<dim3(384), 256, 0, stream>>>(A_ed, Wbf_1d, nullptr, t2, xpT, G3);

  // ---- decoder scan ----
  gru_scan<<<dim3(64), 384, 0, stream>>>(Wv_d, b_hh_d, xpT, hbx_d, nullptr,
                                         A_hs, nullptr, bar + 64, TLEN);

  // ---- logits (direct to d_out) + in-place log_softmax ----
  gemm_bf16<3, 16><<<dim3(4000), 256, 0, stream>>>(A_hs, Wbf_o, b_out, nullptr, out, VOCAB);
  log_softmax_rows<<<dim3(NB * TLEN), 256, 0, stream>>>(out);
}

// Round 6
// 949.985 us; speedup vs baseline: 4.2692x; 1.0790x over previous
//
#include <hip/hip_runtime.h>
#include <stdint.h>
#include <stddef.h>

#define VOCAB 32000
#define HID   1024
#define NB    32
#define SLEN  64
#define TLEN  64
#define G3    3072

typedef float          f32x4  __attribute__((ext_vector_type(4)));
typedef float          f32x2  __attribute__((ext_vector_type(2)));
typedef __bf16         bf16x8 __attribute__((ext_vector_type(8)));
typedef unsigned short u16x8  __attribute__((ext_vector_type(8)));
typedef unsigned short u16x4  __attribute__((ext_vector_type(4)));
typedef unsigned int   u32x4  __attribute__((ext_vector_type(4)));

union BfPun { u16x8 u; bf16x8 b; };
union CvPun { u32x4 u; bf16x8 b; };

__device__ __forceinline__ unsigned short f2bf(float f) {
  unsigned int u = __builtin_bit_cast(unsigned int, f);
  u += 0x7FFFu + ((u >> 16) & 1u);   // RNE round to bf16
  return (unsigned short)(u >> 16);
}

// async global -> LDS, 16 B per lane (LDS dest must be wave-uniform base + lane*16)
__device__ __forceinline__ void gld_lds16(const unsigned short* g, unsigned short* l) {
  __builtin_amdgcn_global_load_lds(
      (const __attribute__((address_space(1))) unsigned int*)g,
      (__attribute__((address_space(3))) unsigned int*)l,
      16, 0, 0);
}

// ---------------- converts / gathers / init ----------------

__global__ __launch_bounds__(256) void cvt_bf16(const float* __restrict__ in,
                                                unsigned short* __restrict__ out) {
  size_t idx = ((size_t)blockIdx.x * 256 + threadIdx.x) * 4;
  f32x4 v = *(const f32x4*)(in + idx);
  u16x4 o;
  o[0] = f2bf(v[0]); o[1] = f2bf(v[1]); o[2] = f2bf(v[2]); o[3] = f2bf(v[3]);
  *(u16x4*)(out + idx) = o;
}

// W_ih_d [3072][2048] -> W1 (cols 0..1023), W2 (cols 1024..2047), both bf16 [3072][1024]
__global__ __launch_bounds__(256) void cvt_split_d(const float* __restrict__ Wd,
                                                   unsigned short* __restrict__ W1,
                                                   unsigned short* __restrict__ W2) {
  int r = blockIdx.x, q = threadIdx.x;
  const float* src = Wd + (size_t)r * 2048;
  f32x4 v1 = *(const f32x4*)(src + q * 4);
  f32x4 v2 = *(const f32x4*)(src + 1024 + q * 4);
  u16x4 o1, o2;
  o1[0]=f2bf(v1[0]); o1[1]=f2bf(v1[1]); o1[2]=f2bf(v1[2]); o1[3]=f2bf(v1[3]);
  o2[0]=f2bf(v2[0]); o2[1]=f2bf(v2[1]); o2[2]=f2bf(v2[2]); o2[3]=f2bf(v2[3]);
  *(u16x4*)(W1 + (size_t)r * 1024 + q * 4) = o1;
  *(u16x4*)(W2 + (size_t)r * 1024 + q * 4) = o2;
}

// W_hh [3H][H] fp32 -> fragment-linear bf16: Wv[blk][g][ks][lane][8]
__global__ __launch_bounds__(128) void cvt_whh_frag(const float* __restrict__ W,
                                                    unsigned short* __restrict__ Wv) {
  int r = blockIdx.x;              // 0..3071
  int g = r >> 10, i = r & 1023, blk = i >> 4, il = i & 15;
  int q = threadIdx.x;             // 8-elem chunk 0..127
  int ks = q >> 2, ksub = q & 3, lane = il + ksub * 16;
  f32x4 v0 = *(const f32x4*)(W + (size_t)r * HID + q * 8);
  f32x4 v1 = *(const f32x4*)(W + (size_t)r * HID + q * 8 + 4);
  u16x8 o;
  o[0]=f2bf(v0[0]); o[1]=f2bf(v0[1]); o[2]=f2bf(v0[2]); o[3]=f2bf(v0[3]);
  o[4]=f2bf(v1[0]); o[5]=f2bf(v1[1]); o[6]=f2bf(v1[2]); o[7]=f2bf(v1[3]);
  size_t dst = ((((size_t)blk * 3 + g) * 32 + ks) * 64 + lane) * 8;
  *(u16x8*)(Wv + dst) = o;
}

__global__ __launch_bounds__(256) void gather_embed(const int* __restrict__ seqs,
                                                    const float* __restrict__ emb,
                                                    unsigned short* __restrict__ Aout,
                                                    int relu) {
  int r = blockIdx.x, q = threadIdx.x;
  int tok = seqs[r];
  f32x4 v = *(const f32x4*)(emb + (size_t)tok * HID + q * 4);
  if (relu) {
    v[0]=fmaxf(v[0],0.f); v[1]=fmaxf(v[1],0.f); v[2]=fmaxf(v[2],0.f); v[3]=fmaxf(v[3],0.f);
  }
  u16x4 o; o[0]=f2bf(v[0]); o[1]=f2bf(v[1]); o[2]=f2bf(v[2]); o[3]=f2bf(v[3]);
  *(u16x4*)(Aout + (size_t)r * HID + q * 4) = o;
}

// relu(thought) -> bf16, rows 32..127 zero-padded
__global__ __launch_bounds__(256) void gather_thought(const float* __restrict__ hfin,
                                                      unsigned short* __restrict__ Aout) {
  int r = blockIdx.x, q = threadIdx.x;
  u16x4 o = {0, 0, 0, 0};
  if (r < NB) {
    f32x4 v = *(const f32x4*)(hfin + (size_t)r * HID + q * 4);
    o[0]=f2bf(fmaxf(v[0],0.f)); o[1]=f2bf(fmaxf(v[1],0.f));
    o[2]=f2bf(fmaxf(v[2],0.f)); o[3]=f2bf(fmaxf(v[3],0.f));
  }
  *(u16x4*)(Aout + (size_t)r * HID + q * 4) = o;
}

__global__ __launch_bounds__(256) void zero_f32(float* __restrict__ p) {
  p[blockIdx.x * 256 + threadIdx.x] = 0.f;
}

// ---------------- bf16 MFMA GEMM: C = A[M,1024] * B[N,1024]^T (+ epilogue) ----------------
// 128x128 tile, BK=32, global_load_lds width-16 staging (m97 structure).
// 1-D grid; XCD-chunked swizzle + (MT x 4) supertile.
template<int MODE, int MT>
__global__ __launch_bounds__(256) void gemm_bf16(const unsigned short* __restrict__ A,
                                                 const unsigned short* __restrict__ Bw,
                                                 const float* __restrict__ bias,
                                                 const float* __restrict__ add2,
                                                 float* __restrict__ out, int N) {
  __shared__ unsigned short Abuf[128 * 32];
  __shared__ unsigned short Bbuf[128 * 32];
  const int K = HID;
  int tid = threadIdx.x, lane = tid & 63, wid = tid >> 6;
  int nwg = gridDim.x;
  int u = (blockIdx.x & 7) * (nwg >> 3) + (blockIdx.x >> 3);
  int g = u / (MT * 4);
  int r_ = u - g * (MT * 4);
  int bm = r_ % MT;
  int bn = g * 4 + r_ / MT;
  int wrow = wid >> 1, wcol = wid & 1;
  f32x4 zero4 = {0.f, 0.f, 0.f, 0.f};
  f32x4 acc[4][4];
#pragma unroll
  for (int i = 0; i < 4; ++i)
#pragma unroll
    for (int j = 0; j < 4; ++j) acc[i][j] = zero4;

  int srow = tid >> 2, spart = tid & 3;
  const unsigned short* Ag = A + ((size_t)bm * 128 + srow) * K + spart * 8;
  const unsigned short* Bg = Bw + ((size_t)bn * 128 + srow) * K + spart * 8;
  unsigned short* As = Abuf + tid * 8;       // linear: lane*16B within wave
  unsigned short* Bs = Bbuf + tid * 8;

  for (int ks = 0; ks < 32; ++ks) {
    int k0 = ks * 32;
    __syncthreads();                          // prev MFMA ds_reads done
    gld_lds16(Ag + k0, As);
    gld_lds16(Ag + (size_t)64 * K + k0, As + 64 * 32);
    gld_lds16(Bg + k0, Bs);
    gld_lds16(Bg + (size_t)64 * K + k0, Bs + 64 * 32);
    __syncthreads();                          // vmcnt(0) drain -> LDS valid
    bf16x8 af[4], bfr[4];
#pragma unroll
    for (int mi = 0; mi < 4; ++mi) {
      BfPun tpun;
      tpun.u = *(const u16x8*)(Abuf + (wrow * 64 + mi * 16 + (lane & 15)) * 32 + (lane >> 4) * 8);
      af[mi] = tpun.b;
    }
#pragma unroll
    for (int ni = 0; ni < 4; ++ni) {
      BfPun tpun;
      tpun.u = *(const u16x8*)(Bbuf + (wcol * 64 + ni * 16 + (lane & 15)) * 32 + (lane >> 4) * 8);
      bfr[ni] = tpun.b;
    }
#pragma unroll
    for (int mi = 0; mi < 4; ++mi)
#pragma unroll
      for (int ni = 0; ni < 4; ++ni)
        acc[mi][ni] = __builtin_amdgcn_mfma_f32_16x16x32_bf16(af[mi], bfr[ni], acc[mi][ni], 0, 0, 0);
  }

#pragma unroll
  for (int mi = 0; mi < 4; ++mi) {
    int rb = bm * 128 + wrow * 64 + mi * 16 + ((lane >> 4) << 2);
#pragma unroll
    for (int ni = 0; ni < 4; ++ni) {
      int c = bn * 128 + wcol * 64 + ni * 16 + (lane & 15);
#pragma unroll
      for (int e = 0; e < 4; ++e) {
        int r = rb + e;
        float v = acc[mi][ni][e];
        if (MODE == 0) {
          out[(size_t)r * N + c] = v + bias[c];
        } else if (MODE == 1) {
          int t = r & 63, b = r >> 6;
          int gg = c >> 10, ci = c & 1023;
          out[(((size_t)t * 3 + gg) * NB + b) * HID + ci] = v + bias[c];
        } else if (MODE == 2) {
          int t = r & 63, b = r >> 6;
          int gg = c >> 10, ci = c & 1023;
          out[(((size_t)t * 3 + gg) * NB + b) * HID + ci] = v + add2[(size_t)b * G3 + c];
        } else {
          int b = r & 31, t = r >> 5;
          out[((size_t)b * TLEN + t) * VOCAB + c] = v + bias[c];
        }
      }
    }
  }
}

// ---------------- persistent GRU scan (MFMA, fragment-linear layouts) ----------------
__global__ __launch_bounds__(384, 1) void gru_scan(
    const unsigned short* __restrict__ Wv,   // [64][3][32][64][8] bf16
    const float* __restrict__ b_hh,
    const float* __restrict__ xpT,           // [T][3][NB][HID]
    unsigned short* __restrict__ hbx,        // [nsteps][2][32][64][8] write-once
    const int* __restrict__ lens,            // null => no freeze (decoder)
    unsigned short* __restrict__ hs_out,     // null for encoder; [T*NB][HID] bf16
    float* __restrict__ hfin,                // final h fp32 (encoder) or null
    int* __restrict__ bar, int nsteps) {     // bar[t]: arrival counters, zeroed
  __shared__ unsigned short Wlds[49152];     // 96 KB
  __shared__ float gh[48][33];
  __shared__ float h32[32][16];
  __shared__ float bhh_s[48];
  __shared__ int   lens_s[32];
  int tid = threadIdx.x, lane = tid & 63, w = tid >> 6;
  int g = w >> 1, part = w & 1;
  int blk = blockIdx.x, i0 = blk * 16;

  if (tid < 32) lens_s[tid] = lens ? lens[tid] : 0x7fffffff;
  if (tid >= 64 && tid < 112) {
    int q = tid - 64;
    bhh_s[q] = b_hh[(size_t)(q >> 4) * HID + i0 + (q & 15)];
  }
  if (tid < 256) h32[tid >> 3][((tid & 7) * 2)] = 0.f;
  if (tid < 256) h32[tid >> 3][((tid & 7) * 2) + 1] = 0.f;

  // stage W fragment slice into LDS (one time)
  {
    const unsigned short* Wsrc = Wv + (size_t)blk * 49152;
    for (int j = tid; j < 6144; j += 384)
      *(u16x8*)(Wlds + (size_t)j * 8) = *(const u16x8*)(Wsrc + (size_t)j * 8);
  }
  __syncthreads();

  int eb = tid >> 3, eil = (tid & 7) * 2;
  f32x2 xr2 = {0.f, 0.f}, xz2 = {0.f, 0.f}, xn2 = {0.f, 0.f};
  if (tid < 256) {
    const float* xb = xpT + (size_t)eb * HID + i0 + eil;
    xr2 = *(const f32x2*)(xb);
    xz2 = *(const f32x2*)(xb + (size_t)NB * HID);
    xn2 = *(const f32x2*)(xb + (size_t)2 * NB * HID);
  }

  for (int t = 0; t < nsteps; ++t) {
    f32x4 acc = {0.f, 0.f, 0.f, 0.f};
    if (t > 0) {
      const unsigned short* hp = hbx + (size_t)(t - 1) * 32768 + part * 16384 + lane * 8;
      u32x4 pb[8];
#pragma unroll
      for (int j = 0; j < 8; ++j) pb[j] = *(const u32x4*)(hp + (size_t)j * 512);
#pragma unroll
      for (int ks = 0; ks < 32; ++ks) {
        BfPun a_;
        a_.u = *(const u16x8*)(Wlds + ((size_t)(g * 32 + ks) * 64 + lane) * 8);
        CvPun cv; cv.u = pb[ks & 7];
        if (ks + 8 < 32) pb[ks & 7] = *(const u32x4*)(hp + (size_t)(ks + 8) * 512);
        acc = __builtin_amdgcn_mfma_f32_16x16x32_bf16(a_.b, cv.b, acc, 0, 0, 0);
      }
    }
    {
      int il4 = (lane >> 4) * 4, cb = part * 16 + (lane & 15);
#pragma unroll
      for (int e = 0; e < 4; ++e) gh[g * 16 + il4 + e][cb] = acc[e];
    }
    __syncthreads();

    if (tid < 256) {
      float sr0 = gh[eil][eb],      sr1 = gh[eil + 1][eb];
      float sz0 = gh[16 + eil][eb], sz1 = gh[16 + eil + 1][eb];
      float sn0 = gh[32 + eil][eb], sn1 = gh[32 + eil + 1][eb];
      float rg0 = 1.f / (1.f + __expf(-(xr2[0] + sr0 + bhh_s[eil])));
      float rg1 = 1.f / (1.f + __expf(-(xr2[1] + sr1 + bhh_s[eil + 1])));
      float zg0 = 1.f / (1.f + __expf(-(xz2[0] + sz0 + bhh_s[16 + eil])));
      float zg1 = 1.f / (1.f + __expf(-(xz2[1] + sz1 + bhh_s[16 + eil + 1])));
      float ng0 = tanhf(xn2[0] + rg0 * (sn0 + bhh_s[32 + eil]));
      float ng1 = tanhf(xn2[1] + rg1 * (sn1 + bhh_s[32 + eil + 1]));
      float h0o = h32[eb][eil], h1o = h32[eb][eil + 1];
      float hn0 = (1.f - zg0) * ng0 + zg0 * h0o;
      float hn1 = (1.f - zg1) * ng1 + zg1 * h1o;
      if (t >= lens_s[eb]) { hn0 = h0o; hn1 = h1o; }   // packed-seq freeze
      h32[eb][eil] = hn0; h32[eb][eil + 1] = hn1;
      unsigned int pk = (unsigned int)f2bf(hn0) | ((unsigned int)f2bf(hn1) << 16);
      int k = i0 + eil;
      int ksf = k >> 5, lnf = (eb & 15) + ((k >> 3) & 3) * 16, sub = k & 7;
      unsigned short* dst = hbx + (size_t)t * 32768 + (size_t)(eb >> 4) * 16384
                            + (size_t)ksf * 512 + lnf * 8 + sub;
      __hip_atomic_store((unsigned int*)dst, pk, __ATOMIC_RELAXED, __HIP_MEMORY_SCOPE_AGENT);
      if (hs_out)
        *(unsigned int*)(hs_out + ((size_t)t * NB + eb) * HID + k) = pk;
      if (t + 1 < nsteps) {
        const float* xb = xpT + ((size_t)(t + 1) * 3 * NB + eb) * HID + i0 + eil;
        xr2 = *(const f32x2*)(xb);
        xz2 = *(const f32x2*)(xb + (size_t)NB * HID);
        xn2 = *(const f32x2*)(xb + (size_t)2 * NB * HID);
      }
    }

    if (t + 1 < nsteps) {
      __syncthreads();   // vmcnt(0) drain: hbx stores visible at L3
      if (tid == 0) {
        __hip_atomic_fetch_add(&bar[t], 1, __ATOMIC_RELAXED, __HIP_MEMORY_SCOPE_AGENT);
        while (__hip_atomic_load(&bar[t], __ATOMIC_RELAXED, __HIP_MEMORY_SCOPE_AGENT) < (int)gridDim.x)
          __builtin_amdgcn_s_sleep(1);
      }
      __syncthreads();
    }
  }

  if (hfin && tid < 256) {
    f32x2 hv; hv[0] = h32[eb][eil]; hv[1] = h32[eb][eil + 1];
    *(f32x2*)(hfin + (size_t)eb * HID + i0 + eil) = hv;
  }
}

// ---------------- LDS-staged in-place row log_softmax on d_out [2048 x 32000] ----------------
// One block per row; row staged in 125 KB LDS -> single global read + single write.
__global__ __launch_bounds__(1024, 1) void log_softmax_lds(float* __restrict__ out) {
  __shared__ float rowbuf[VOCAB];            // 128000 B
  __shared__ float ms[16], ss[16];
  size_t row = blockIdx.x;
  float* p = out + row * VOCAB;
  const f32x4* p4 = (const f32x4*)p;
  int tid = threadIdx.x;
  float m = -3.0e38f, s = 0.f;
  for (int j = tid; j < VOCAB / 4; j += 1024) {
    f32x4 v = p4[j];
    *(f32x4*)(rowbuf + j * 4) = v;
#pragma unroll
    for (int e = 0; e < 4; ++e) {
      float x = v[e];
      float nm = fmaxf(m, x);
      s = s * __expf(m - nm) + __expf(x - nm);
      m = nm;
    }
  }
#pragma unroll
  for (int off = 1; off < 64; off <<= 1) {
    float m2 = __shfl_xor(m, off, 64);
    float s2 = __shfl_xor(s, off, 64);
    float nm = fmaxf(m, m2);
    s = s * __expf(m - nm) + s2 * __expf(m2 - nm);
    m = nm;
  }
  if ((tid & 63) == 0) { ms[tid >> 6] = m; ss[tid >> 6] = s; }
  __syncthreads();
  float M = -3.0e38f;
#pragma unroll
  for (int i = 0; i < 16; ++i) M = fmaxf(M, ms[i]);
  float S = 0.f;
#pragma unroll
  for (int i = 0; i < 16; ++i) S += ss[i] * __expf(ms[i] - M);
  float lse = M + __logf(S);
  f32x4* o4 = (f32x4*)p;
  for (int j = tid; j < VOCAB / 4; j += 1024) {
    f32x4 v = *(const f32x4*)(rowbuf + j * 4);
    v[0] -= lse; v[1] -= lse; v[2] -= lse; v[3] -= lse;
    o4[j] = v;
  }
}

// ---------------- host ----------------

extern "C" void kernel_launch(void* const* d_in, const int* in_sizes, int n_in,
                              void* d_out, int out_size, void* d_ws, size_t ws_size,
                              hipStream_t stream) {
  (void)in_sizes; (void)n_in; (void)out_size; (void)ws_size;
  const int*   input_seqs  = (const int*)d_in[0];
  const int*   target_seqs = (const int*)d_in[1];
  const int*   input_lens  = (const int*)d_in[2];
  const float* emb_enc = (const float*)d_in[3];
  const float* W_ih_e  = (const float*)d_in[4];
  const float* W_hh_e  = (const float*)d_in[5];
  const float* b_ih_e  = (const float*)d_in[6];
  const float* b_hh_e  = (const float*)d_in[7];
  const float* emb_dec = (const float*)d_in[8];
  const float* W_ih_d  = (const float*)d_in[9];
  const float* W_hh_d  = (const float*)d_in[10];
  const float* b_ih_d  = (const float*)d_in[11];
  const float* b_hh_d  = (const float*)d_in[12];
  const float* W_out   = (const float*)d_in[13];
  const float* b_out   = (const float*)d_in[14];
  float* out = (float*)d_out;

  char* p = (char*)d_ws;
  auto take = [&](size_t n) { char* q = p; p += (n + 255) & ~(size_t)255; return q; };
  unsigned short* Wbf_e  = (unsigned short*)take((size_t)G3 * HID * 2);
  unsigned short* Wbf_1d = (unsigned short*)take((size_t)G3 * HID * 2);
  unsigned short* Wbf_2d = (unsigned short*)take((size_t)G3 * HID * 2);
  unsigned short* Wbf_o  = (unsigned short*)take((size_t)VOCAB * HID * 2);
  unsigned short* Wv_e   = (unsigned short*)take((size_t)G3 * HID * 2);
  unsigned short* Wv_d   = (unsigned short*)take((size_t)G3 * HID * 2);
  unsigned short* A_ed   = (unsigned short*)take((size_t)2048 * HID * 2);
  unsigned short* A_th   = (unsigned short*)take((size_t)128 * HID * 2);
  unsigned short* A_hs   = (unsigned short*)take((size_t)2048 * HID * 2);
  float* xpT = (float*)take((size_t)64 * 3 * NB * HID * 4);
  float* t2  = (float*)take((size_t)128 * G3 * 4);
  unsigned short* hbx_e = (unsigned short*)take((size_t)SLEN * NB * HID * 2);
  unsigned short* hbx_d = (unsigned short*)take((size_t)TLEN * NB * HID * 2);
  int*   bar  = (int*)take(1024);              // bar_enc[64] | bar_dec[64]
  float* hfin = (float*)take((size_t)NB * HID * 4);

  // weight converts (fp32 -> bf16)
  cvt_bf16<<<dim3((G3 * HID) / 1024), 256, 0, stream>>>(W_ih_e, Wbf_e);
  cvt_split_d<<<dim3(G3), 256, 0, stream>>>(W_ih_d, Wbf_1d, Wbf_2d);
  cvt_bf16<<<dim3((VOCAB * HID) / 1024), 256, 0, stream>>>(W_out, Wbf_o);
  cvt_whh_frag<<<dim3(G3), 128, 0, stream>>>(W_hh_e, Wv_e);
  cvt_whh_frag<<<dim3(G3), 128, 0, stream>>>(W_hh_d, Wv_d);
  zero_f32<<<dim3(1), 256, 0, stream>>>((float*)bar);   // both scans' barrier counters

  // ---- encoder ----
  gather_embed<<<dim3(NB * SLEN), 256, 0, stream>>>(input_seqs, emb_enc, A_ed, 0);
  gemm_bf16<1, 16><<<dim3(384), 256, 0, stream>>>(A_ed, Wbf_e, b_ih_e, nullptr, xpT, G3);
  gru_scan<<<dim3(64), 384, 0, stream>>>(Wv_e, b_hh_e, xpT, hbx_e, input_lens,
                                         nullptr, hfin, bar, SLEN);

  // ---- decoder pre ----
  gather_thought<<<dim3(128), 256, 0, stream>>>(hfin, A_th);
  gemm_bf16<0, 1><<<dim3(24), 256, 0, stream>>>(A_th, Wbf_2d, b_ih_d, nullptr, t2, G3);
  gather_embed<<<dim3(NB * TLEN), 256, 0, stream>>>(target_seqs, emb_dec, A_ed, 1);
  gemm_bf16<2, 16><<<dim3(384), 256, 0, stream>>>(A_ed, Wbf_1d, nullptr, t2, xpT, G3);

  // ---- decoder scan ----
  gru_scan<<<dim3(64), 384, 0, stream>>>(Wv_d, b_hh_d, xpT, hbx_d, nullptr,
                                         A_hs, nullptr, bar + 64, TLEN);

  // ---- logits (direct to d_out) + in-place log_softmax ----
  gemm_bf16<3, 16><<<dim3(4000), 256, 0, stream>>>(A_hs, Wbf_o, b_out, nullptr, out, VOCAB);
  log_softmax_lds<<<dim3(NB * TLEN), 1024, 0, stream>>>(out);
}